// Round 13
// baseline (792.695 us; speedup 1.0000x reference)
//
#include <hip/hip_runtime.h>

#define EPS_BN 1e-5f

typedef short bf16x8 __attribute__((ext_vector_type(8)));
typedef float f32x4 __attribute__((ext_vector_type(4)));

__device__ __forceinline__ unsigned short f2b(float f)
{
    union { float f; unsigned int u; } c; c.f = f;
    unsigned int u = c.u + 0x7FFFu + ((c.u >> 16) & 1u);
    return (unsigned short)(u >> 16);
}
__device__ __forceinline__ float blo(unsigned int u)
{
    union { unsigned int u; float f; } c; c.u = u << 16; return c.f;
}
__device__ __forceinline__ float bhi(unsigned int u)
{
    union { unsigned int u; float f; } c; c.u = u & 0xFFFF0000u; return c.f;
}

// acc += a.lo*sel.lo + a.hi*sel.hi  (bf16 pairs, f32 accum) — 1 instr per bf16 value
__device__ __forceinline__ float dot2bf(float acc, unsigned int a, unsigned int sel)
{
    asm("v_dot2_f32_bf16 %0, %1, %2, %0" : "+v"(acc) : "v"(a), "v"(sel));
    return acc;
}

// async global->LDS, 16B per lane; LDS dest = wave-uniform base + lane*16
__device__ __forceinline__ void async_ld16(const unsigned short* g, unsigned short* l)
{
    __builtin_amdgcn_global_load_lds(
        (const __attribute__((address_space(1))) unsigned int*)g,
        (__attribute__((address_space(3))) unsigned int*)l, 16, 0, 0);
}

// relation / type index helpers (branchless compare-sums)
__device__ __forceinline__ int relof_e(int e) {
    return (e>=500000)+(e>=900000)+(e>=1050000)+(e>=1450000)+(e>=1950000)+(e>=2350000);
}
__device__ __forceinline__ int relof_n(int i) {
    return (i>=10000)+(i>=60000)+(i>=63000)+(i>=73000)+(i>=93000)+(i>=113000);
}
__device__ __forceinline__ int eoff_of(int r) {
    return r<1?0 : r<2?500000 : r<3?900000 : r<4?1050000 : r<5?1450000 : r<6?1950000 : 2350000;
}
__device__ __forceinline__ int coff_of(int r) {
    return r<1?0 : r<2?10000 : r<3?60000 : r<4?63000 : r<5?73000 : r<6?93000 : 113000;
}
__device__ __forceinline__ int typ_of(int row) { return (row>=20000)+(row>=70000)+(row>=80000); }
__device__ __forceinline__ float invR_of(int t){ return t<1?5e-5f : t<2?2e-5f : t<3?1e-4f : (1.0f/3000.0f); }

struct Graph { const int* src[7]; const int* dst[7]; };

__device__ __forceinline__ void relptrs(const Graph& g, int r, const int*& sp, const int*& dp)
{
    sp = g.src[0]; dp = g.dst[0];
    if (r==1){sp=g.src[1];dp=g.dst[1];}
    if (r==2){sp=g.src[2];dp=g.dst[2];}
    if (r==3){sp=g.src[3];dp=g.dst[3];}
    if (r==4){sp=g.src[4];dp=g.dst[4];}
    if (r==5){sp=g.src[5];dp=g.dst[5];}
    if (r==6){sp=g.src[6];dp=g.dst[6];}
}

// ---------------------------------------------------------------- degree histogram (all rels, 1 launch)
// nt loads: edge stream is single-use — don't let it evict the hot icnt lines
__global__ void count_all(Graph g, int* __restrict__ icnt)
{
    for (int e = blockIdx.x * blockDim.x + threadIdx.x; e < 2500000; e += gridDim.x * blockDim.x) {
        int r = relof_e(e);
        const int *sp, *dp; relptrs(g, r, sp, dp);
        int le = e - eoff_of(r);
        int d = __builtin_nontemporal_load(dp + le);
        atomicAdd(&icnt[coff_of(r) + d], 1);
    }
}

// ---------------------------------------------------------------- 3-phase global scan
__global__ __launch_bounds__(1024)
void scan1(const int* __restrict__ icnt, int* __restrict__ scanbuf, int* __restrict__ bsums)
{
    __shared__ int lds[1024];
    int tid = threadIdx.x;
    int gid = blockIdx.x * 1024 + tid;
    int v = (gid < 163000) ? icnt[gid] : 0;
    lds[tid] = v;
    __syncthreads();
    for (int d = 1; d < 1024; d <<= 1) {
        int t = (tid >= d) ? lds[tid - d] : 0;
        __syncthreads();
        lds[tid] += t;
        __syncthreads();
    }
    scanbuf[gid] = lds[tid];                  // inclusive within block
    if (tid == 1023) bsums[blockIdx.x] = lds[1023];
}

__global__ __launch_bounds__(256)
void scan2(int* __restrict__ bsums)          // exclusive scan of 160 partials, in place
{
    __shared__ int lds[256];
    int tid = threadIdx.x;
    int v = (tid < 160) ? bsums[tid] : 0;
    lds[tid] = v;
    __syncthreads();
    for (int d = 1; d < 256; d <<= 1) {
        int t = (tid >= d) ? lds[tid - d] : 0;
        __syncthreads();
        lds[tid] += t;
        __syncthreads();
    }
    bsums[tid] = tid ? lds[tid - 1] : 0;
}

// fixup: rowptrG (global cumulative), cur (insert cursors), inv (1/max(deg,1)),
// sliceid: 8-way partition of dst space with EQUAL EDGE COUNT per slice (for fill locality)
__global__ __launch_bounds__(256)
void scan_fix(const int* __restrict__ icnt, const int* __restrict__ scanbuf,
              const int* __restrict__ bsums, int* __restrict__ rowptrG,
              int* __restrict__ cur, float* __restrict__ inv,
              unsigned char* __restrict__ sliceid)
{
    int idx = blockIdx.x * blockDim.x + threadIdx.x;
    if (idx > 163000) return;
    int G = bsums[idx >> 10] + ((idx & 1023) ? scanbuf[idx - 1] : 0);
    rowptrG[idx] = G;
    if (idx < 163000) {
        cur[idx] = G;
        inv[idx] = 1.0f / (float)max(icnt[idx], 1);
        int s = G / 312500;                    // 2.5M edges / 8 slices
        sliceid[idx] = (unsigned char)(s > 7 ? 7 : s);
    }
}

// ---------------------------------------------------------------- CSR fill, XCD-sliced
// nt loads on the 8x-scanned edge stream: keep the hot cursor/CSR lines resident in L2
// so they fill before eviction (round-12 profile: WRITE 106 MB for 10 MB CSR = eviction thrash)
__global__ void fill_all(Graph g, const unsigned char* __restrict__ sliceid,
                         int* __restrict__ cur, int* __restrict__ csr)
{
    const int slice = blockIdx.x & 7;
    const int bper  = gridDim.x >> 3;
    const int bidx  = blockIdx.x >> 3;
    for (int e = bidx * blockDim.x + threadIdx.x; e < 2500000; e += bper * blockDim.x) {
        int r = relof_e(e);
        const int *sp, *dp; relptrs(g, r, sp, dp);
        int le = e - eoff_of(r);
        int d = __builtin_nontemporal_load(dp + le);
        int gidx = coff_of(r) + d;
        if (sliceid[gidx] == slice) {
            int s = __builtin_nontemporal_load(sp + le);
            csr[atomicAdd(&cur[gidx], 1)] = s;
        }
    }
}

// ---------------------------------------------------------------- f32 -> bf16, all 4 types in one launch
__global__ void tob16_all(const float* __restrict__ x0, const float* __restrict__ x1,
                          const float* __restrict__ x2, const float* __restrict__ x3,
                          unsigned short* __restrict__ xb)
{
    const int total = 83000 * 32;             // float4 chunks (128 f32/row)
    for (int i = blockIdx.x * blockDim.x + threadIdx.x; i < total; i += gridDim.x * blockDim.x) {
        int row = i >> 5, c4 = i & 31;
        int t = typ_of(row);
        const float* xp = (t == 0) ? x0 : (t == 1) ? x1 : (t == 2) ? x2 : x3;
        int lrow = row - (t < 1 ? 0 : t < 2 ? 20000 : t < 3 ? 70000 : 80000);
        float4 v = ((const float4*)(xp + (size_t)lrow * 128))[c4];
        uint2 o;
        o.x = (unsigned int)f2b(v.x) | ((unsigned int)f2b(v.y) << 16);
        o.y = (unsigned int)f2b(v.z) | ((unsigned int)f2b(v.w) << 16);
        ((uint2*)(xb + (size_t)row * 128))[c4] = o;
    }
}

// ---------------------------------------------------------------- fused gather-mean, all relations in one launch
// dot2-based accumulate (1 instr/value), predicated uniform body (no serial tail)
struct GatherCfg {
    const unsigned short* X[7];
    const int* rowptrG;
    const int* csr;
    const float* inv;
    unsigned short* agg;
};

template <int D>
__global__ __launch_bounds__(256)
void gather_all(GatherCfg c)
{
    constexpr int LPE = D / 8;        // lanes per edge (one uint4 = 16B each)
    constexpr int EPW = 64 / LPE;     // edges per wave concurrently (4 or 2)
    constexpr int U   = 4;            // loads in flight per lane
    int wid = (blockIdx.x * blockDim.x + threadIdx.x) >> 6;
    if (wid >= 163000) return;
    int l = threadIdx.x & 63;
    int q = l & (LPE - 1);
    int gg = l / LPE;
    int r = relof_n(wid);
    const unsigned short* X = c.X[0];
    if (r==1) X=c.X[1];
    if (r==2) X=c.X[2];
    if (r==3) X=c.X[3];
    if (r==4) X=c.X[4];
    if (r==5) X=c.X[5];
    if (r==6) X=c.X[6];
    const unsigned short* Xq = X + q * 8;
    const int* csr = c.csr;
    int beg = c.rowptrG[wid], end = c.rowptrG[wid + 1];
    float acc[8] = {0.f,0.f,0.f,0.f,0.f,0.f,0.f,0.f};
    if (beg < end) {
        const int last = end - 1;
        for (int it = beg; it < end; it += U * EPW) {
            uint4 v[U]; unsigned int sl[U];
#pragma unroll
            for (int j = 0; j < U; ++j) {
                int idx = it + j * EPW + gg;
                int e = idx < last ? idx : last;      // clamp: overhang re-reads last edge
                int s = csr[e];
                v[j]  = *(const uint4*)(Xq + (size_t)s * D);
                sl[j] = (idx <= last) ? 0x00003F80u : 0u;   // bf16 1.0 selector, 0 if masked
            }
#pragma unroll
            for (int j = 0; j < U; ++j) {
                unsigned int lo = sl[j], hi = sl[j] << 16;
                acc[0] = dot2bf(acc[0], v[j].x, lo);
                acc[1] = dot2bf(acc[1], v[j].x, hi);
                acc[2] = dot2bf(acc[2], v[j].y, lo);
                acc[3] = dot2bf(acc[3], v[j].y, hi);
                acc[4] = dot2bf(acc[4], v[j].z, lo);
                acc[5] = dot2bf(acc[5], v[j].z, hi);
                acc[6] = dot2bf(acc[6], v[j].w, lo);
                acc[7] = dot2bf(acc[7], v[j].w, hi);
            }
        }
    }
#pragma unroll
    for (int k = 0; k < 8; ++k) {
        if (LPE == 16) acc[k] += __shfl_xor(acc[k], 16);
        acc[k] += __shfl_xor(acc[k], 32);
    }
    if (l < LPE) {
        float inv = c.inv[wid];
        uint4 o;
        o.x = (unsigned int)f2b(acc[0]*inv) | ((unsigned int)f2b(acc[1]*inv) << 16);
        o.y = (unsigned int)f2b(acc[2]*inv) | ((unsigned int)f2b(acc[3]*inv) << 16);
        o.z = (unsigned int)f2b(acc[4]*inv) | ((unsigned int)f2b(acc[5]*inv) << 16);
        o.w = (unsigned int)f2b(acc[6]*inv) | ((unsigned int)f2b(acc[7]*inv) << 16);
        *(uint4*)(c.agg + (size_t)wid * D + q * 8) = o;
    }
}

// ---------------------------------------------------------------- weight prep: sum roots, transpose to [N][K] bf16
// (biases dropped: a per-column constant cancels exactly in train-mode BN's v - mu)
__global__ void wtrans_kernel(const float* __restrict__ Wr, const float* __restrict__ Wl,
                              unsigned short* __restrict__ wsumT, unsigned short* __restrict__ WlT,
                              int K)
{
    const int nrel[4]  = {2, 2, 2, 1};
    const int rl[4][2] = {{4,5},{1,6},{0,3},{2,2}};
    int per = 256 * K;
    int tot = 11 * per;
    for (int idx = blockIdx.x * blockDim.x + threadIdx.x; idx < tot;
         idx += gridDim.x * blockDim.x) {
        if (idx < 4 * per) {
            int t = idx / per, rem = idx - t * per;
            int n = rem / K, k = rem - n * K;
            float s = Wr[(size_t)rl[t][0] * per + k * 256 + n];
            if (nrel[t] > 1) s += Wr[(size_t)rl[t][1] * per + k * 256 + n];
            wsumT[idx] = f2b(s);
        } else {
            int j = idx - 4 * per;
            int r = j / per, rem = j - r * per;
            int n = rem / K, k = rem - n * K;
            WlT[j] = f2b(Wl[(size_t)r * per + k * 256 + n]);
        }
    }
}

// ---------------------------------------------------------------- fused MFMA GEMM, 128x256 tile, 8 waves (2x4),
// global_load_lds staging with pre-swizzled source (rule #21), BN-stats fused in epilogue
struct GemmBatch {
    const unsigned short* A0[4];
    const unsigned short* A1[4];
    const unsigned short* A2[4];
    const unsigned short* B0[4];
    const unsigned short* B1[4];
    const unsigned short* B2[4];
    float* outF;
    unsigned short* outB;
    float* stats;
    int R[4]; int bcum[4]; int rowoff[4]; int nsrc[4];
    int K, kshift, outf32;
};

__global__ __launch_bounds__(512, 4)
void gemm_mfma(GemmBatch g)
{
    __shared__ __align__(16) unsigned short Atile[2][128 * 32];   // 16 KB
    __shared__ __align__(16) unsigned short Btile[2][256 * 32];   // 32 KB

    const int tid = threadIdx.x;
    const int bz = blockIdx.x;
    const int t = (bz >= g.bcum[1]) + (bz >= g.bcum[2]) + (bz >= g.bcum[3]);
    const int bm = (bz - g.bcum[t]) << 7;
    const int w = tid >> 6, l = tid & 63;
    const int wr = w >> 2, wc = w & 3;          // 2x4 waves, wave tile 64 rows x 64 cols

    const int R = g.R[t];
    const int K = g.K, kshift = g.kshift, kmask = K - 1;
    const unsigned short* A0t = g.A0[t];
    const unsigned short* A1t = g.A1[t];
    const unsigned short* A2t = g.A2[t];
    const unsigned short* B0t = g.B0[t];
    const unsigned short* B1t = g.B1[t];
    const unsigned short* B2t = g.B2[t];
    const int steps = (g.nsrc[t] * K) >> 5;

    const int rloc = tid >> 2;                                    // 0..127
    const int swz  = (((tid & 3) ^ ((tid >> 3) & 3)) << 3);       // source k-offset (elems)
    const int srowA = min(bm + rloc, R - 1);                      // clamp: garbage only feeds rows >= R
    const int wseg  = w << 9;                                     // w*512 ushorts = 1KB per wave

    auto stage = [&](int st, int buf) {
        int kglob = st << 5;
        int s  = kglob >> kshift;
        int kk = kglob & kmask;
        const unsigned short* As = (s == 0) ? A0t : (s == 1) ? A1t : A2t;
        const unsigned short* Bs = (s == 0) ? B0t : (s == 1) ? B1t : B2t;
        async_ld16(As + (size_t)srowA * K + kk + swz, &Atile[buf][wseg]);
        async_ld16(Bs + (size_t)rloc  * K + kk + swz, &Btile[buf][wseg]);
        async_ld16(Bs + (size_t)(128 + rloc) * K + kk + swz, &Btile[buf][4096 + wseg]);
    };

    f32x4 acc[4][4];
#pragma unroll
    for (int i = 0; i < 4; ++i)
#pragma unroll
        for (int j = 0; j < 4; ++j)
            acc[i][j] = (f32x4){0.f, 0.f, 0.f, 0.f};

    const int ck = l >> 4;
    const int ra = wr * 64 + (l & 15);
    const int aoff = ra * 32 + ((ck ^ ((ra >> 1) & 3)) << 3);
    const int rb = wc * 64 + (l & 15);
    const int boff = rb * 32 + ((ck ^ ((rb >> 1) & 3)) << 3);   // +16 rows keeps swz invariant

    stage(0, 0);
    __syncthreads();
    int cur = 0;
    for (int st = 0; st < steps; ++st) {
        if (st + 1 < steps) stage(st + 1, cur ^ 1);
        const unsigned short* At = Atile[cur];
        const unsigned short* Bt = Btile[cur];
        bf16x8 af[4], bfr[4];
#pragma unroll
        for (int i = 0; i < 4; ++i) {
            af[i]  = *(const bf16x8*)(At + aoff + i * 512);
            bfr[i] = *(const bf16x8*)(Bt + boff + i * 512);
        }
#pragma unroll
        for (int mi = 0; mi < 4; ++mi)
#pragma unroll
            for (int ni = 0; ni < 4; ++ni)
                acc[mi][ni] = __builtin_amdgcn_mfma_f32_16x16x32_bf16(
                    af[mi], bfr[ni], acc[mi][ni], 0, 0, 0);
        __syncthreads();     // drains next-tile global_load_lds + this tile's ds_reads
        cur ^= 1;
    }

    // epilogue: write output + per-column BN partial sums (sum, sumsq)
    const int orow0 = bm + wr * 64 + ((l >> 4) << 2);
    const int ocol0 = wc * 64 + (l & 15);
#pragma unroll
    for (int ni = 0; ni < 4; ++ni) {
        int col = ocol0 + ni * 16;
        float ps = 0.f, pq = 0.f;
#pragma unroll
        for (int mi = 0; mi < 4; ++mi) {
#pragma unroll
            for (int j = 0; j < 4; ++j) {
                int row = orow0 + mi * 16 + j;
                float v = acc[mi][ni][j];
                if (row < R) {
                    size_t o = (size_t)(g.rowoff[t] + row) * 256 + col;
                    if (g.outf32) g.outF[o] = v;
                    else          g.outB[o] = f2b(v);
                } else v = 0.f;
                ps += v; pq += v * v;
            }
        }
        ps += __shfl_xor(ps, 16); ps += __shfl_xor(ps, 32);
        pq += __shfl_xor(pq, 16); pq += __shfl_xor(pq, 32);
        if (l < 16) {
            atomicAdd(&g.stats[t * 512 + col], ps);
            atomicAdd(&g.stats[t * 512 + 256 + col], pq);
        }
    }
}

// ---------------------------------------------------------------- BatchNorm apply (train-mode) + ReLU
template <int F32>
__global__ __launch_bounds__(256)
void bn_apply_all(void* __restrict__ Hv, const float* __restrict__ stats,
                  const float* __restrict__ gg, const float* __restrict__ be)
{
    const int total4 = 83000 * 64;
    for (int i4 = blockIdx.x * blockDim.x + threadIdx.x; i4 < total4;
         i4 += gridDim.x * blockDim.x) {
        int row = i4 >> 6;
        int c4  = (i4 & 63) << 2;
        int t   = typ_of(row);
        float invR = invR_of(t);
        const float* st = stats + t * 512;
        float vin[4];
        if (F32) {
            float4 v = *(const float4*)((const float*)Hv + (size_t)row * 256 + c4);
            vin[0]=v.x; vin[1]=v.y; vin[2]=v.z; vin[3]=v.w;
        } else {
            uint2 u = *(const uint2*)((const unsigned short*)Hv + (size_t)row * 256 + c4);
            vin[0]=blo(u.x); vin[1]=bhi(u.x); vin[2]=blo(u.y); vin[3]=bhi(u.y);
        }
        float vout[4];
#pragma unroll
        for (int k = 0; k < 4; ++k) {
            int c = c4 + k;
            float mu  = st[c] * invR;
            float var = st[256 + c] * invR - mu * mu;
            float sc  = rsqrtf(var + EPS_BN) * gg[c];
            float v   = (vin[k] - mu) * sc + be[c];
            vout[k] = fmaxf(v, 0.f);
        }
        if (F32) {
            float4 o; o.x=vout[0]; o.y=vout[1]; o.z=vout[2]; o.w=vout[3];
            *(float4*)((float*)Hv + (size_t)row * 256 + c4) = o;
        } else {
            uint2 o;
            o.x = (unsigned int)f2b(vout[0]) | ((unsigned int)f2b(vout[1]) << 16);
            o.y = (unsigned int)f2b(vout[2]) | ((unsigned int)f2b(vout[3]) << 16);
            *(uint2*)((unsigned short*)Hv + (size_t)row * 256 + c4) = o;
        }
    }
}

// ---------------------------------------------------------------- host
extern "C" void kernel_launch(void* const* d_in, const int* in_sizes, int n_in,
                              void* d_out, int out_size, void* d_ws, size_t ws_size,
                              hipStream_t stream)
{
    static const int Nn[4]   = {20000, 50000, 10000, 3000};
    static const int roff[4] = {0, 20000, 70000, 80000};
    static const int rst[7]  = {0, 0, 1, 1, 2, 1, 3};
    static const int coff[7] = {0, 10000, 60000, 63000, 73000, 93000, 113000};
    static const int trels[4][2] = {{4,5},{1,6},{0,3},{2,2}};
    static const int tnrel[4]    = {2, 2, 2, 1};
    const int CNT_TOTAL = 163000;

    const float* x[4];
    for (int t = 0; t < 4; ++t) x[t] = (const float*)d_in[t];
    Graph graph;
    for (int i = 0; i < 7; ++i) {
        graph.src[i] = (const int*)d_in[4 + 2 * i];
        graph.dst[i] = (const int*)d_in[5 + 2 * i];
    }
    const float* W1l = (const float*)d_in[18];
    const float* W1r = (const float*)d_in[19];
    const float* W2l = (const float*)d_in[21];
    const float* W2r = (const float*)d_in[22];
    const float* g1  = (const float*)d_in[24];
    const float* be1 = (const float*)d_in[25];
    const float* g2  = (const float*)d_in[26];
    const float* be2 = (const float*)d_in[27];
    float* out = (float*)d_out;
    (void)n_in; (void)in_sizes; (void)out_size; (void)ws_size;

    // ---- workspace carve (~143 MB)
    char* w = (char*)d_ws;
    size_t off = 0;
    auto carve = [&](size_t bytes) -> void* {
        void* p = (void*)(w + off);
        off = (off + bytes + 255) & ~(size_t)255;
        return p;
    };
    int*   icnt    = (int*)carve((size_t)CNT_TOTAL * 4);
    int*   cur     = (int*)carve((size_t)CNT_TOTAL * 4);
    int*   rowptrG = (int*)carve((size_t)(CNT_TOTAL + 1) * 4);
    int*   csr     = (int*)carve((size_t)2500000 * 4);
    int*   scanbuf = (int*)carve((size_t)163840 * 4);
    int*   bsums   = (int*)carve((size_t)256 * 4);
    float* inv     = (float*)carve((size_t)CNT_TOTAL * 4);
    float* stats   = (float*)carve((size_t)2 * 4 * 512 * 4);   // [layer][type][sum|sumsq][256]
    unsigned char* sliceid = (unsigned char*)carve((size_t)CNT_TOTAL);
    unsigned short* wsumT1 = (unsigned short*)carve((size_t)4 * 256 * 128 * 2);
    unsigned short* WlT1   = (unsigned short*)carve((size_t)7 * 256 * 128 * 2);
    unsigned short* wsumT2 = (unsigned short*)carve((size_t)4 * 256 * 256 * 2);
    unsigned short* WlT2   = (unsigned short*)carve((size_t)7 * 256 * 256 * 2);
    unsigned short* U      = (unsigned short*)carve((size_t)163000 * 256 * 2); // union region
    unsigned short* hb     = (unsigned short*)carve((size_t)83000 * 256 * 2);
    unsigned short* xb    = U;                        // layer-1: bf16 inputs (21.25 MB)
    unsigned short* aggL1 = U + (size_t)83000 * 128;  // layer-1 agg (after xb)
    unsigned short* aggL2 = U;                        // layer-2 agg (xb dead by then)
    float* stats1 = stats;
    float* stats2 = stats + 2048;

    // ---- CSR build (globally-cumulative rowptr; shared by both layers)
    hipMemsetAsync(icnt, 0, (size_t)CNT_TOTAL * 4, stream);
    hipMemsetAsync(stats, 0, (size_t)2 * 4 * 512 * 4, stream);
    count_all<<<2048, 256, 0, stream>>>(graph, icnt);
    scan1<<<160, 1024, 0, stream>>>(icnt, scanbuf, bsums);
    scan2<<<1, 256, 0, stream>>>(bsums);
    scan_fix<<<(CNT_TOTAL + 256) / 256, 256, 0, stream>>>(icnt, scanbuf, bsums,
                                                          rowptrG, cur, inv, sliceid);
    fill_all<<<2048, 256, 0, stream>>>(graph, sliceid, cur, csr);

    // ---- x -> bf16 (one launch) + weight prep (both layers)
    tob16_all<<<2048, 256, 0, stream>>>(x[0], x[1], x[2], x[3], xb);
    wtrans_kernel<<<1024, 256, 0, stream>>>(W1r, W1l, wsumT1, WlT1, 128);
    wtrans_kernel<<<1024, 256, 0, stream>>>(W2r, W2l, wsumT2, WlT2, 256);

    for (int layer = 0; layer < 2; ++layer) {
        const int K = layer ? 256 : 128;
        const float* gg = layer ? g2  : g1;
        const float* be = layer ? be2 : be1;
        unsigned short* agg = layer ? aggL2 : aggL1;
        unsigned short* wsumT = layer ? wsumT2 : wsumT1;
        unsigned short* WlT   = layer ? WlT2   : WlT1;
        float* st = layer ? stats2 : stats1;

        GatherCfg gc;
        for (int r = 0; r < 7; ++r)
            gc.X[r] = layer ? (hb + (size_t)roff[rst[r]] * 256)
                            : (xb + (size_t)roff[rst[r]] * 128);
        gc.rowptrG = rowptrG; gc.csr = csr; gc.inv = inv; gc.agg = agg;
        if (layer == 0) gather_all<128><<<40750, 256, 0, stream>>>(gc);
        else            gather_all<256><<<40750, 256, 0, stream>>>(gc);

        GemmBatch gb;
        for (int t = 0; t < 4; ++t) {
            gb.A0[t] = layer ? (hb + (size_t)roff[t] * 256) : (xb + (size_t)roff[t] * 128);
            gb.A1[t] = agg + (size_t)coff[trels[t][0]] * K;
            gb.A2[t] = (tnrel[t] > 1) ? (agg + (size_t)coff[trels[t][1]] * K) : gb.A1[t];
            gb.B0[t] = wsumT + (size_t)t * 256 * K;
            gb.B1[t] = WlT + (size_t)trels[t][0] * 256 * K;
            gb.B2[t] = (tnrel[t] > 1) ? (WlT + (size_t)trels[t][1] * 256 * K) : gb.B1[t];
            gb.R[t] = Nn[t];
            gb.rowoff[t] = roff[t];
            gb.nsrc[t] = 1 + tnrel[t];
        }
        gb.bcum[0] = 0; gb.bcum[1] = 157; gb.bcum[2] = 548; gb.bcum[3] = 627;
        gb.outF = out; gb.outB = hb;
        gb.stats = st;
        gb.K = K; gb.kshift = layer ? 8 : 7; gb.outf32 = layer;
        gemm_mfma<<<651, 512, 0, stream>>>(gb);

        if (layer == 0) bn_apply_all<0><<<2048, 256, 0, stream>>>(hb, st, gg, be);
        else            bn_apply_all<1><<<2048, 256, 0, stream>>>(out, st, gg, be);
    }
}

// Round 14
// 774.312 us; speedup vs baseline: 1.0237x; 1.0237x over previous
//
#include <hip/hip_runtime.h>

#define EPS_BN 1e-5f

typedef short bf16x8 __attribute__((ext_vector_type(8)));
typedef float f32x4 __attribute__((ext_vector_type(4)));

__device__ __forceinline__ unsigned short f2b(float f)
{
    union { float f; unsigned int u; } c; c.f = f;
    unsigned int u = c.u + 0x7FFFu + ((c.u >> 16) & 1u);
    return (unsigned short)(u >> 16);
}
__device__ __forceinline__ float blo(unsigned int u)
{
    union { unsigned int u; float f; } c; c.u = u << 16; return c.f;
}
__device__ __forceinline__ float bhi(unsigned int u)
{
    union { unsigned int u; float f; } c; c.u = u & 0xFFFF0000u; return c.f;
}

// acc += a.lo*sel.lo + a.hi*sel.hi  (bf16 pairs, f32 accum) — 1 instr per bf16 value
__device__ __forceinline__ float dot2bf(float acc, unsigned int a, unsigned int sel)
{
    asm("v_dot2_f32_bf16 %0, %1, %2, %0" : "+v"(acc) : "v"(a), "v"(sel));
    return acc;
}

// async global->LDS, 16B per lane; LDS dest = wave-uniform base + lane*16
__device__ __forceinline__ void async_ld16(const unsigned short* g, unsigned short* l)
{
    __builtin_amdgcn_global_load_lds(
        (const __attribute__((address_space(1))) unsigned int*)g,
        (__attribute__((address_space(3))) unsigned int*)l, 16, 0, 0);
}

// relation / type index helpers (branchless compare-sums)
__device__ __forceinline__ int relof_e(int e) {
    return (e>=500000)+(e>=900000)+(e>=1050000)+(e>=1450000)+(e>=1950000)+(e>=2350000);
}
__device__ __forceinline__ int relof_n(int i) {
    return (i>=10000)+(i>=60000)+(i>=63000)+(i>=73000)+(i>=93000)+(i>=113000);
}
__device__ __forceinline__ int eoff_of(int r) {
    return r<1?0 : r<2?500000 : r<3?900000 : r<4?1050000 : r<5?1450000 : r<6?1950000 : 2350000;
}
__device__ __forceinline__ int coff_of(int r) {
    return r<1?0 : r<2?10000 : r<3?60000 : r<4?63000 : r<5?73000 : r<6?93000 : 113000;
}
__device__ __forceinline__ int typ_of(int row) { return (row>=20000)+(row>=70000)+(row>=80000); }
__device__ __forceinline__ float invR_of(int t){ return t<1?5e-5f : t<2?2e-5f : t<3?1e-4f : (1.0f/3000.0f); }

struct Graph { const int* src[7]; const int* dst[7]; };

__device__ __forceinline__ void relptrs(const Graph& g, int r, const int*& sp, const int*& dp)
{
    sp = g.src[0]; dp = g.dst[0];
    if (r==1){sp=g.src[1];dp=g.dst[1];}
    if (r==2){sp=g.src[2];dp=g.dst[2];}
    if (r==3){sp=g.src[3];dp=g.dst[3];}
    if (r==4){sp=g.src[4];dp=g.dst[4];}
    if (r==5){sp=g.src[5];dp=g.dst[5];}
    if (r==6){sp=g.src[6];dp=g.dst[6];}
}

// ---------------------------------------------------------------- degree histogram (all rels, 1 launch)
__global__ void count_all(Graph g, int* __restrict__ icnt)
{
    for (int e = blockIdx.x * blockDim.x + threadIdx.x; e < 2500000; e += gridDim.x * blockDim.x) {
        int r = relof_e(e);
        const int *sp, *dp; relptrs(g, r, sp, dp);
        int le = e - eoff_of(r);
        atomicAdd(&icnt[coff_of(r) + dp[le]], 1);
    }
}

// ---------------------------------------------------------------- 3-phase global scan
__global__ __launch_bounds__(1024)
void scan1(const int* __restrict__ icnt, int* __restrict__ scanbuf, int* __restrict__ bsums)
{
    __shared__ int lds[1024];
    int tid = threadIdx.x;
    int gid = blockIdx.x * 1024 + tid;
    int v = (gid < 163000) ? icnt[gid] : 0;
    lds[tid] = v;
    __syncthreads();
    for (int d = 1; d < 1024; d <<= 1) {
        int t = (tid >= d) ? lds[tid - d] : 0;
        __syncthreads();
        lds[tid] += t;
        __syncthreads();
    }
    scanbuf[gid] = lds[tid];                  // inclusive within block
    if (tid == 1023) bsums[blockIdx.x] = lds[1023];
}

__global__ __launch_bounds__(256)
void scan2(int* __restrict__ bsums)          // exclusive scan of 160 partials, in place
{
    __shared__ int lds[256];
    int tid = threadIdx.x;
    int v = (tid < 160) ? bsums[tid] : 0;
    lds[tid] = v;
    __syncthreads();
    for (int d = 1; d < 256; d <<= 1) {
        int t = (tid >= d) ? lds[tid - d] : 0;
        __syncthreads();
        lds[tid] += t;
        __syncthreads();
    }
    bsums[tid] = tid ? lds[tid - 1] : 0;
}

// fixup: rowptrG (global cumulative), cur (insert cursors), inv (1/max(deg,1)),
// cuts[b] (b=1..7): first dst index whose cumulative edge count reaches b*312500.
// slice(d) = #{b: d >= cut[b]} == min(G(d)/312500, 7) — computable by 7 register compares.
__global__ __launch_bounds__(256)
void scan_fix(const int* __restrict__ icnt, const int* __restrict__ scanbuf,
              const int* __restrict__ bsums, int* __restrict__ rowptrG,
              int* __restrict__ cur, float* __restrict__ inv, int* __restrict__ cuts)
{
    const int QS = 312500;
    int idx = blockIdx.x * blockDim.x + threadIdx.x;
    if (idx > 163000) return;
    int G = bsums[idx >> 10] + ((idx & 1023) ? scanbuf[idx - 1] : 0);
    rowptrG[idx] = G;
    if (idx < 163000) {
        cur[idx] = G;
        inv[idx] = 1.0f / (float)max(icnt[idx], 1);
    }
    if (idx >= 1 && idx <= 163000) {
        int Gp = G - icnt[idx - 1];           // G(idx-1)
#pragma unroll
        for (int b = 1; b <= 7; ++b) {
            int thr = b * QS;
            if (Gp < thr && G >= thr) cuts[b] = idx;   // unique writer per b
        }
    }
}

// ---------------------------------------------------------------- CSR fill, XCD-sliced
// slice computed from 7 register-held cut points (no random table lookup);
// per-dst cursors keep atomic contention spread (round-9 lesson).
__global__ void fill_all(Graph g, const int* __restrict__ cuts,
                         int* __restrict__ cur, int* __restrict__ csr)
{
    const int slice = blockIdx.x & 7;
    const int bper  = gridDim.x >> 3;
    const int bidx  = blockIdx.x >> 3;
    int c1 = cuts[1], c2 = cuts[2], c3 = cuts[3], c4 = cuts[4],
        c5 = cuts[5], c6 = cuts[6], c7 = cuts[7];
    for (int e = bidx * blockDim.x + threadIdx.x; e < 2500000; e += bper * blockDim.x) {
        int r = relof_e(e);
        const int *sp, *dp; relptrs(g, r, sp, dp);
        int le = e - eoff_of(r);
        int gidx = coff_of(r) + dp[le];
        int s = (gidx >= c1) + (gidx >= c2) + (gidx >= c3) + (gidx >= c4)
              + (gidx >= c5) + (gidx >= c6) + (gidx >= c7);
        if (s == slice)
            csr[atomicAdd(&cur[gidx], 1)] = sp[le];
    }
}

// ---------------------------------------------------------------- f32 -> bf16, all 4 types in one launch
__global__ void tob16_all(const float* __restrict__ x0, const float* __restrict__ x1,
                          const float* __restrict__ x2, const float* __restrict__ x3,
                          unsigned short* __restrict__ xb)
{
    const int total = 83000 * 32;             // float4 chunks (128 f32/row)
    for (int i = blockIdx.x * blockDim.x + threadIdx.x; i < total; i += gridDim.x * blockDim.x) {
        int row = i >> 5, c4 = i & 31;
        int t = typ_of(row);
        const float* xp = (t == 0) ? x0 : (t == 1) ? x1 : (t == 2) ? x2 : x3;
        int lrow = row - (t < 1 ? 0 : t < 2 ? 20000 : t < 3 ? 70000 : 80000);
        float4 v = ((const float4*)(xp + (size_t)lrow * 128))[c4];
        uint2 o;
        o.x = (unsigned int)f2b(v.x) | ((unsigned int)f2b(v.y) << 16);
        o.y = (unsigned int)f2b(v.z) | ((unsigned int)f2b(v.w) << 16);
        ((uint2*)(xb + (size_t)row * 128))[c4] = o;
    }
}

// ---------------------------------------------------------------- fused gather-mean, all relations in one launch
// dot2-based accumulate (1 instr/value), predicated uniform body (no serial tail)
struct GatherCfg {
    const unsigned short* X[7];
    const int* rowptrG;
    const int* csr;
    const float* inv;
    unsigned short* agg;
};

template <int D>
__global__ __launch_bounds__(256)
void gather_all(GatherCfg c)
{
    constexpr int LPE = D / 8;        // lanes per edge (one uint4 = 16B each)
    constexpr int EPW = 64 / LPE;     // edges per wave concurrently (4 or 2)
    constexpr int U   = 4;            // loads in flight per lane
    int wid = (blockIdx.x * blockDim.x + threadIdx.x) >> 6;
    if (wid >= 163000) return;
    int l = threadIdx.x & 63;
    int q = l & (LPE - 1);
    int gg = l / LPE;
    int r = relof_n(wid);
    const unsigned short* X = c.X[0];
    if (r==1) X=c.X[1];
    if (r==2) X=c.X[2];
    if (r==3) X=c.X[3];
    if (r==4) X=c.X[4];
    if (r==5) X=c.X[5];
    if (r==6) X=c.X[6];
    const unsigned short* Xq = X + q * 8;
    const int* csr = c.csr;
    int beg = c.rowptrG[wid], end = c.rowptrG[wid + 1];
    float acc[8] = {0.f,0.f,0.f,0.f,0.f,0.f,0.f,0.f};
    if (beg < end) {
        const int last = end - 1;
        for (int it = beg; it < end; it += U * EPW) {
            uint4 v[U]; unsigned int sl[U];
#pragma unroll
            for (int j = 0; j < U; ++j) {
                int idx = it + j * EPW + gg;
                int e = idx < last ? idx : last;      // clamp: overhang re-reads last edge
                int s = csr[e];
                v[j]  = *(const uint4*)(Xq + (size_t)s * D);
                sl[j] = (idx <= last) ? 0x00003F80u : 0u;   // bf16 1.0 selector, 0 if masked
            }
#pragma unroll
            for (int j = 0; j < U; ++j) {
                unsigned int lo = sl[j], hi = sl[j] << 16;
                acc[0] = dot2bf(acc[0], v[j].x, lo);
                acc[1] = dot2bf(acc[1], v[j].x, hi);
                acc[2] = dot2bf(acc[2], v[j].y, lo);
                acc[3] = dot2bf(acc[3], v[j].y, hi);
                acc[4] = dot2bf(acc[4], v[j].z, lo);
                acc[5] = dot2bf(acc[5], v[j].z, hi);
                acc[6] = dot2bf(acc[6], v[j].w, lo);
                acc[7] = dot2bf(acc[7], v[j].w, hi);
            }
        }
    }
#pragma unroll
    for (int k = 0; k < 8; ++k) {
        if (LPE == 16) acc[k] += __shfl_xor(acc[k], 16);
        acc[k] += __shfl_xor(acc[k], 32);
    }
    if (l < LPE) {
        float inv = c.inv[wid];
        uint4 o;
        o.x = (unsigned int)f2b(acc[0]*inv) | ((unsigned int)f2b(acc[1]*inv) << 16);
        o.y = (unsigned int)f2b(acc[2]*inv) | ((unsigned int)f2b(acc[3]*inv) << 16);
        o.z = (unsigned int)f2b(acc[4]*inv) | ((unsigned int)f2b(acc[5]*inv) << 16);
        o.w = (unsigned int)f2b(acc[6]*inv) | ((unsigned int)f2b(acc[7]*inv) << 16);
        *(uint4*)(c.agg + (size_t)wid * D + q * 8) = o;
    }
}

// ---------------------------------------------------------------- weight prep: sum roots, transpose to [N][K] bf16
// (biases dropped: a per-column constant cancels exactly in train-mode BN's v - mu)
__global__ void wtrans_kernel(const float* __restrict__ Wr, const float* __restrict__ Wl,
                              unsigned short* __restrict__ wsumT, unsigned short* __restrict__ WlT,
                              int K)
{
    const int nrel[4]  = {2, 2, 2, 1};
    const int rl[4][2] = {{4,5},{1,6},{0,3},{2,2}};
    int per = 256 * K;
    int tot = 11 * per;
    for (int idx = blockIdx.x * blockDim.x + threadIdx.x; idx < tot;
         idx += gridDim.x * blockDim.x) {
        if (idx < 4 * per) {
            int t = idx / per, rem = idx - t * per;
            int n = rem / K, k = rem - n * K;
            float s = Wr[(size_t)rl[t][0] * per + k * 256 + n];
            if (nrel[t] > 1) s += Wr[(size_t)rl[t][1] * per + k * 256 + n];
            wsumT[idx] = f2b(s);
        } else {
            int j = idx - 4 * per;
            int r = j / per, rem = j - r * per;
            int n = rem / K, k = rem - n * K;
            WlT[j] = f2b(Wl[(size_t)r * per + k * 256 + n]);
        }
    }
}

// ---------------------------------------------------------------- fused MFMA GEMM, 128x256 tile, 8 waves (2x4),
// global_load_lds staging with pre-swizzled source (rule #21), BN-stats fused in epilogue
struct GemmBatch {
    const unsigned short* A0[4];
    const unsigned short* A1[4];
    const unsigned short* A2[4];
    const unsigned short* B0[4];
    const unsigned short* B1[4];
    const unsigned short* B2[4];
    float* outF;
    unsigned short* outB;
    float* stats;
    int R[4]; int bcum[4]; int rowoff[4]; int nsrc[4];
    int K, kshift, outf32;
};

__global__ __launch_bounds__(512, 4)
void gemm_mfma(GemmBatch g)
{
    __shared__ __align__(16) unsigned short Atile[2][128 * 32];   // 16 KB
    __shared__ __align__(16) unsigned short Btile[2][256 * 32];   // 32 KB

    const int tid = threadIdx.x;
    const int bz = blockIdx.x;
    const int t = (bz >= g.bcum[1]) + (bz >= g.bcum[2]) + (bz >= g.bcum[3]);
    const int bm = (bz - g.bcum[t]) << 7;
    const int w = tid >> 6, l = tid & 63;
    const int wr = w >> 2, wc = w & 3;          // 2x4 waves, wave tile 64 rows x 64 cols

    const int R = g.R[t];
    const int K = g.K, kshift = g.kshift, kmask = K - 1;
    const unsigned short* A0t = g.A0[t];
    const unsigned short* A1t = g.A1[t];
    const unsigned short* A2t = g.A2[t];
    const unsigned short* B0t = g.B0[t];
    const unsigned short* B1t = g.B1[t];
    const unsigned short* B2t = g.B2[t];
    const int steps = (g.nsrc[t] * K) >> 5;

    const int rloc = tid >> 2;                                    // 0..127
    const int swz  = (((tid & 3) ^ ((tid >> 3) & 3)) << 3);       // source k-offset (elems)
    const int srowA = min(bm + rloc, R - 1);                      // clamp: garbage only feeds rows >= R
    const int wseg  = w << 9;                                     // w*512 ushorts = 1KB per wave

    auto stage = [&](int st, int buf) {
        int kglob = st << 5;
        int s  = kglob >> kshift;
        int kk = kglob & kmask;
        const unsigned short* As = (s == 0) ? A0t : (s == 1) ? A1t : A2t;
        const unsigned short* Bs = (s == 0) ? B0t : (s == 1) ? B1t : B2t;
        async_ld16(As + (size_t)srowA * K + kk + swz, &Atile[buf][wseg]);
        async_ld16(Bs + (size_t)rloc  * K + kk + swz, &Btile[buf][wseg]);
        async_ld16(Bs + (size_t)(128 + rloc) * K + kk + swz, &Btile[buf][4096 + wseg]);
    };

    f32x4 acc[4][4];
#pragma unroll
    for (int i = 0; i < 4; ++i)
#pragma unroll
        for (int j = 0; j < 4; ++j)
            acc[i][j] = (f32x4){0.f, 0.f, 0.f, 0.f};

    const int ck = l >> 4;
    const int ra = wr * 64 + (l & 15);
    const int aoff = ra * 32 + ((ck ^ ((ra >> 1) & 3)) << 3);
    const int rb = wc * 64 + (l & 15);
    const int boff = rb * 32 + ((ck ^ ((rb >> 1) & 3)) << 3);   // +16 rows keeps swz invariant

    stage(0, 0);
    __syncthreads();
    int cur = 0;
    for (int st = 0; st < steps; ++st) {
        if (st + 1 < steps) stage(st + 1, cur ^ 1);
        const unsigned short* At = Atile[cur];
        const unsigned short* Bt = Btile[cur];
        bf16x8 af[4], bfr[4];
#pragma unroll
        for (int i = 0; i < 4; ++i) {
            af[i]  = *(const bf16x8*)(At + aoff + i * 512);
            bfr[i] = *(const bf16x8*)(Bt + boff + i * 512);
        }
#pragma unroll
        for (int mi = 0; mi < 4; ++mi)
#pragma unroll
            for (int ni = 0; ni < 4; ++ni)
                acc[mi][ni] = __builtin_amdgcn_mfma_f32_16x16x32_bf16(
                    af[mi], bfr[ni], acc[mi][ni], 0, 0, 0);
        __syncthreads();     // drains next-tile global_load_lds + this tile's ds_reads
        cur ^= 1;
    }

    // epilogue: write output + per-column BN partial sums (sum, sumsq)
    const int orow0 = bm + wr * 64 + ((l >> 4) << 2);
    const int ocol0 = wc * 64 + (l & 15);
#pragma unroll
    for (int ni = 0; ni < 4; ++ni) {
        int col = ocol0 + ni * 16;
        float ps = 0.f, pq = 0.f;
#pragma unroll
        for (int mi = 0; mi < 4; ++mi) {
#pragma unroll
            for (int j = 0; j < 4; ++j) {
                int row = orow0 + mi * 16 + j;
                float v = acc[mi][ni][j];
                if (row < R) {
                    size_t o = (size_t)(g.rowoff[t] + row) * 256 + col;
                    if (g.outf32) g.outF[o] = v;
                    else          g.outB[o] = f2b(v);
                } else v = 0.f;
                ps += v; pq += v * v;
            }
        }
        ps += __shfl_xor(ps, 16); ps += __shfl_xor(ps, 32);
        pq += __shfl_xor(pq, 16); pq += __shfl_xor(pq, 32);
        if (l < 16) {
            atomicAdd(&g.stats[t * 512 + col], ps);
            atomicAdd(&g.stats[t * 512 + 256 + col], pq);
        }
    }
}

// ---------------------------------------------------------------- BatchNorm apply (train-mode) + ReLU
template <int F32>
__global__ __launch_bounds__(256)
void bn_apply_all(void* __restrict__ Hv, const float* __restrict__ stats,
                  const float* __restrict__ gg, const float* __restrict__ be)
{
    const int total4 = 83000 * 64;
    for (int i4 = blockIdx.x * blockDim.x + threadIdx.x; i4 < total4;
         i4 += gridDim.x * blockDim.x) {
        int row = i4 >> 6;
        int c4  = (i4 & 63) << 2;
        int t   = typ_of(row);
        float invR = invR_of(t);
        const float* st = stats + t * 512;
        float vin[4];
        if (F32) {
            float4 v = *(const float4*)((const float*)Hv + (size_t)row * 256 + c4);
            vin[0]=v.x; vin[1]=v.y; vin[2]=v.z; vin[3]=v.w;
        } else {
            uint2 u = *(const uint2*)((const unsigned short*)Hv + (size_t)row * 256 + c4);
            vin[0]=blo(u.x); vin[1]=bhi(u.x); vin[2]=blo(u.y); vin[3]=bhi(u.y);
        }
        float vout[4];
#pragma unroll
        for (int k = 0; k < 4; ++k) {
            int c = c4 + k;
            float mu  = st[c] * invR;
            float var = st[256 + c] * invR - mu * mu;
            float sc  = rsqrtf(var + EPS_BN) * gg[c];
            float v   = (vin[k] - mu) * sc + be[c];
            vout[k] = fmaxf(v, 0.f);
        }
        if (F32) {
            float4 o; o.x=vout[0]; o.y=vout[1]; o.z=vout[2]; o.w=vout[3];
            *(float4*)((float*)Hv + (size_t)row * 256 + c4) = o;
        } else {
            uint2 o;
            o.x = (unsigned int)f2b(vout[0]) | ((unsigned int)f2b(vout[1]) << 16);
            o.y = (unsigned int)f2b(vout[2]) | ((unsigned int)f2b(vout[3]) << 16);
            *(uint2*)((unsigned short*)Hv + (size_t)row * 256 + c4) = o;
        }
    }
}

// ---------------------------------------------------------------- host
extern "C" void kernel_launch(void* const* d_in, const int* in_sizes, int n_in,
                              void* d_out, int out_size, void* d_ws, size_t ws_size,
                              hipStream_t stream)
{
    static const int Nn[4]   = {20000, 50000, 10000, 3000};
    static const int roff[4] = {0, 20000, 70000, 80000};
    static const int rst[7]  = {0, 0, 1, 1, 2, 1, 3};
    static const int coff[7] = {0, 10000, 60000, 63000, 73000, 93000, 113000};
    static const int trels[4][2] = {{4,5},{1,6},{0,3},{2,2}};
    static const int tnrel[4]    = {2, 2, 2, 1};
    const int CNT_TOTAL = 163000;

    const float* x[4];
    for (int t = 0; t < 4; ++t) x[t] = (const float*)d_in[t];
    Graph graph;
    for (int i = 0; i < 7; ++i) {
        graph.src[i] = (const int*)d_in[4 + 2 * i];
        graph.dst[i] = (const int*)d_in[5 + 2 * i];
    }
    const float* W1l = (const float*)d_in[18];
    const float* W1r = (const float*)d_in[19];
    const float* W2l = (const float*)d_in[21];
    const float* W2r = (const float*)d_in[22];
    const float* g1  = (const float*)d_in[24];
    const float* be1 = (const float*)d_in[25];
    const float* g2  = (const float*)d_in[26];
    const float* be2 = (const float*)d_in[27];
    float* out = (float*)d_out;
    (void)n_in; (void)in_sizes; (void)out_size; (void)ws_size;

    // ---- workspace carve (~143 MB)
    char* w = (char*)d_ws;
    size_t off = 0;
    auto carve = [&](size_t bytes) -> void* {
        void* p = (void*)(w + off);
        off = (off + bytes + 255) & ~(size_t)255;
        return p;
    };
    int*   icnt    = (int*)carve((size_t)CNT_TOTAL * 4);
    int*   cur     = (int*)carve((size_t)CNT_TOTAL * 4);
    int*   rowptrG = (int*)carve((size_t)(CNT_TOTAL + 1) * 4);
    int*   csr     = (int*)carve((size_t)2500000 * 4);
    int*   scanbuf = (int*)carve((size_t)163840 * 4);
    int*   bsums   = (int*)carve((size_t)256 * 4);
    int*   cuts    = (int*)carve((size_t)8 * 4);
    float* inv     = (float*)carve((size_t)CNT_TOTAL * 4);
    float* stats   = (float*)carve((size_t)2 * 4 * 512 * 4);   // [layer][type][sum|sumsq][256]
    unsigned short* wsumT1 = (unsigned short*)carve((size_t)4 * 256 * 128 * 2);
    unsigned short* WlT1   = (unsigned short*)carve((size_t)7 * 256 * 128 * 2);
    unsigned short* wsumT2 = (unsigned short*)carve((size_t)4 * 256 * 256 * 2);
    unsigned short* WlT2   = (unsigned short*)carve((size_t)7 * 256 * 256 * 2);
    unsigned short* U      = (unsigned short*)carve((size_t)163000 * 256 * 2); // union region
    unsigned short* hb     = (unsigned short*)carve((size_t)83000 * 256 * 2);
    unsigned short* xb    = U;                        // layer-1: bf16 inputs (21.25 MB)
    unsigned short* aggL1 = U + (size_t)83000 * 128;  // layer-1 agg (after xb)
    unsigned short* aggL2 = U;                        // layer-2 agg (xb dead by then)
    float* stats1 = stats;
    float* stats2 = stats + 2048;

    // ---- CSR build (globally-cumulative rowptr; shared by both layers)
    hipMemsetAsync(icnt, 0, (size_t)CNT_TOTAL * 4, stream);
    hipMemsetAsync(stats, 0, (size_t)2 * 4 * 512 * 4, stream);
    count_all<<<2048, 256, 0, stream>>>(graph, icnt);
    scan1<<<160, 1024, 0, stream>>>(icnt, scanbuf, bsums);
    scan2<<<1, 256, 0, stream>>>(bsums);
    scan_fix<<<(CNT_TOTAL + 256) / 256, 256, 0, stream>>>(icnt, scanbuf, bsums,
                                                          rowptrG, cur, inv, cuts);
    fill_all<<<2048, 256, 0, stream>>>(graph, cuts, cur, csr);

    // ---- x -> bf16 (one launch) + weight prep (both layers)
    tob16_all<<<2048, 256, 0, stream>>>(x[0], x[1], x[2], x[3], xb);
    wtrans_kernel<<<1024, 256, 0, stream>>>(W1r, W1l, wsumT1, WlT1, 128);
    wtrans_kernel<<<1024, 256, 0, stream>>>(W2r, W2l, wsumT2, WlT2, 256);

    for (int layer = 0; layer < 2; ++layer) {
        const int K = layer ? 256 : 128;
        const float* gg = layer ? g2  : g1;
        const float* be = layer ? be2 : be1;
        unsigned short* agg = layer ? aggL2 : aggL1;
        unsigned short* wsumT = layer ? wsumT2 : wsumT1;
        unsigned short* WlT   = layer ? WlT2   : WlT1;
        float* st = layer ? stats2 : stats1;

        GatherCfg gc;
        for (int r = 0; r < 7; ++r)
            gc.X[r] = layer ? (hb + (size_t)roff[rst[r]] * 256)
                            : (xb + (size_t)roff[rst[r]] * 128);
        gc.rowptrG = rowptrG; gc.csr = csr; gc.inv = inv; gc.agg = agg;
        if (layer == 0) gather_all<128><<<40750, 256, 0, stream>>>(gc);
        else            gather_all<256><<<40750, 256, 0, stream>>>(gc);

        GemmBatch gb;
        for (int t = 0; t < 4; ++t) {
            gb.A0[t] = layer ? (hb + (size_t)roff[t] * 256) : (xb + (size_t)roff[t] * 128);
            gb.A1[t] = agg + (size_t)coff[trels[t][0]] * K;
            gb.A2[t] = (tnrel[t] > 1) ? (agg + (size_t)coff[trels[t][1]] * K) : gb.A1[t];
            gb.B0[t] = wsumT + (size_t)t * 256 * K;
            gb.B1[t] = WlT + (size_t)trels[t][0] * 256 * K;
            gb.B2[t] = (tnrel[t] > 1) ? (WlT + (size_t)trels[t][1] * 256 * K) : gb.B1[t];
            gb.R[t] = Nn[t];
            gb.rowoff[t] = roff[t];
            gb.nsrc[t] = 1 + tnrel[t];
        }
        gb.bcum[0] = 0; gb.bcum[1] = 157; gb.bcum[2] = 548; gb.bcum[3] = 627;
        gb.outF = out; gb.outB = hb;
        gb.stats = st;
        gb.K = K; gb.kshift = layer ? 8 : 7; gb.outf32 = layer;
        gemm_mfma<<<651, 512, 0, stream>>>(gb);

        if (layer == 0) bn_apply_all<0><<<2048, 256, 0, stream>>>(hb, st, gg, be);
        else            bn_apply_all<1><<<2048, 256, 0, stream>>>(out, st, gg, be);
    }
}

// Round 15
// 771.245 us; speedup vs baseline: 1.0278x; 1.0040x over previous
//
#include <hip/hip_runtime.h>

#define EPS_BN 1e-5f

typedef short bf16x8 __attribute__((ext_vector_type(8)));
typedef float f32x4 __attribute__((ext_vector_type(4)));

__device__ __forceinline__ unsigned short f2b(float f)
{
    union { float f; unsigned int u; } c; c.f = f;
    unsigned int u = c.u + 0x7FFFu + ((c.u >> 16) & 1u);
    return (unsigned short)(u >> 16);
}
__device__ __forceinline__ float blo(unsigned int u)
{
    union { unsigned int u; float f; } c; c.u = u << 16; return c.f;
}
__device__ __forceinline__ float bhi(unsigned int u)
{
    union { unsigned int u; float f; } c; c.u = u & 0xFFFF0000u; return c.f;
}

// acc += a.lo*sel.lo + a.hi*sel.hi  (bf16 pairs, f32 accum) — 1 instr per bf16 value
__device__ __forceinline__ float dot2bf(float acc, unsigned int a, unsigned int sel)
{
    asm("v_dot2_f32_bf16 %0, %1, %2, %0" : "+v"(acc) : "v"(a), "v"(sel));
    return acc;
}

// async global->LDS, 16B per lane; LDS dest = wave-uniform base + lane*16
__device__ __forceinline__ void async_ld16(const unsigned short* g, unsigned short* l)
{
    __builtin_amdgcn_global_load_lds(
        (const __attribute__((address_space(1))) unsigned int*)g,
        (__attribute__((address_space(3))) unsigned int*)l, 16, 0, 0);
}

// relation / type index helpers (branchless compare-sums)
__device__ __forceinline__ int relof_e(int e) {
    return (e>=500000)+(e>=900000)+(e>=1050000)+(e>=1450000)+(e>=1950000)+(e>=2350000);
}
__device__ __forceinline__ int relof_n(int i) {
    return (i>=10000)+(i>=60000)+(i>=63000)+(i>=73000)+(i>=93000)+(i>=113000);
}
__device__ __forceinline__ int eoff_of(int r) {
    return r<1?0 : r<2?500000 : r<3?900000 : r<4?1050000 : r<5?1450000 : r<6?1950000 : 2350000;
}
__device__ __forceinline__ int coff_of(int r) {
    return r<1?0 : r<2?10000 : r<3?60000 : r<4?63000 : r<5?73000 : r<6?93000 : 113000;
}
__device__ __forceinline__ int typ_of(int row) { return (row>=20000)+(row>=70000)+(row>=80000); }
__device__ __forceinline__ float invR_of(int t){ return t<1?5e-5f : t<2?2e-5f : t<3?1e-4f : (1.0f/3000.0f); }

struct Graph { const int* src[7]; const int* dst[7]; };

__device__ __forceinline__ void relptrs(const Graph& g, int r, const int*& sp, const int*& dp)
{
    sp = g.src[0]; dp = g.dst[0];
    if (r==1){sp=g.src[1];dp=g.dst[1];}
    if (r==2){sp=g.src[2];dp=g.dst[2];}
    if (r==3){sp=g.src[3];dp=g.dst[3];}
    if (r==4){sp=g.src[4];dp=g.dst[4];}
    if (r==5){sp=g.src[5];dp=g.dst[5];}
    if (r==6){sp=g.src[6];dp=g.dst[6];}
}

// ---------------------------------------------------------------- degree histogram (all rels, 1 launch)
__global__ void count_all(Graph g, int* __restrict__ icnt)
{
    for (int e = blockIdx.x * blockDim.x + threadIdx.x; e < 2500000; e += gridDim.x * blockDim.x) {
        int r = relof_e(e);
        const int *sp, *dp; relptrs(g, r, sp, dp);
        int le = e - eoff_of(r);
        atomicAdd(&icnt[coff_of(r) + dp[le]], 1);
    }
}

// ---------------------------------------------------------------- 3-phase global scan
__global__ __launch_bounds__(1024)
void scan1(const int* __restrict__ icnt, int* __restrict__ scanbuf, int* __restrict__ bsums)
{
    __shared__ int lds[1024];
    int tid = threadIdx.x;
    int gid = blockIdx.x * 1024 + tid;
    int v = (gid < 163000) ? icnt[gid] : 0;
    lds[tid] = v;
    __syncthreads();
    for (int d = 1; d < 1024; d <<= 1) {
        int t = (tid >= d) ? lds[tid - d] : 0;
        __syncthreads();
        lds[tid] += t;
        __syncthreads();
    }
    scanbuf[gid] = lds[tid];                  // inclusive within block
    if (tid == 1023) bsums[blockIdx.x] = lds[1023];
}

__global__ __launch_bounds__(256)
void scan2(int* __restrict__ bsums)          // exclusive scan of 160 partials, in place
{
    __shared__ int lds[256];
    int tid = threadIdx.x;
    int v = (tid < 160) ? bsums[tid] : 0;
    lds[tid] = v;
    __syncthreads();
    for (int d = 1; d < 256; d <<= 1) {
        int t = (tid >= d) ? lds[tid - d] : 0;
        __syncthreads();
        lds[tid] += t;
        __syncthreads();
    }
    bsums[tid] = tid ? lds[tid - 1] : 0;
}

// fixup: rowptrG (global cumulative), cur (insert cursors), inv (1/max(deg,1)),
// cuts[b] (b=1..7): first dst index whose cumulative edge count reaches b*312500.
// slice(d) = #{b: d >= cut[b]} == min(G(d)/312500, 7) — computable by 7 register compares.
__global__ __launch_bounds__(256)
void scan_fix(const int* __restrict__ icnt, const int* __restrict__ scanbuf,
              const int* __restrict__ bsums, int* __restrict__ rowptrG,
              int* __restrict__ cur, float* __restrict__ inv, int* __restrict__ cuts)
{
    const int QS = 312500;
    int idx = blockIdx.x * blockDim.x + threadIdx.x;
    if (idx > 163000) return;
    int G = bsums[idx >> 10] + ((idx & 1023) ? scanbuf[idx - 1] : 0);
    rowptrG[idx] = G;
    if (idx < 163000) {
        cur[idx] = G;
        inv[idx] = 1.0f / (float)max(icnt[idx], 1);
    }
    if (idx >= 1 && idx <= 163000) {
        int Gp = G - icnt[idx - 1];           // G(idx-1)
#pragma unroll
        for (int b = 1; b <= 7; ++b) {
            int thr = b * QS;
            if (Gp < thr && G >= thr) cuts[b] = idx;   // unique writer per b
        }
    }
}

// ---------------------------------------------------------------- CSR fill, XCD-sliced
// slice computed from 7 register-held cut points (no random table lookup);
// per-dst cursors keep atomic contention spread (round-9 lesson).
__global__ void fill_all(Graph g, const int* __restrict__ cuts,
                         int* __restrict__ cur, int* __restrict__ csr)
{
    const int slice = blockIdx.x & 7;
    const int bper  = gridDim.x >> 3;
    const int bidx  = blockIdx.x >> 3;
    int c1 = cuts[1], c2 = cuts[2], c3 = cuts[3], c4 = cuts[4],
        c5 = cuts[5], c6 = cuts[6], c7 = cuts[7];
    for (int e = bidx * blockDim.x + threadIdx.x; e < 2500000; e += bper * blockDim.x) {
        int r = relof_e(e);
        const int *sp, *dp; relptrs(g, r, sp, dp);
        int le = e - eoff_of(r);
        int gidx = coff_of(r) + dp[le];
        int s = (gidx >= c1) + (gidx >= c2) + (gidx >= c3) + (gidx >= c4)
              + (gidx >= c5) + (gidx >= c6) + (gidx >= c7);
        if (s == slice)
            csr[atomicAdd(&cur[gidx], 1)] = sp[le];
    }
}

// ---------------------------------------------------------------- f32 -> bf16, all 4 types in one launch
__global__ void tob16_all(const float* __restrict__ x0, const float* __restrict__ x1,
                          const float* __restrict__ x2, const float* __restrict__ x3,
                          unsigned short* __restrict__ xb)
{
    const int total = 83000 * 32;             // float4 chunks (128 f32/row)
    for (int i = blockIdx.x * blockDim.x + threadIdx.x; i < total; i += gridDim.x * blockDim.x) {
        int row = i >> 5, c4 = i & 31;
        int t = typ_of(row);
        const float* xp = (t == 0) ? x0 : (t == 1) ? x1 : (t == 2) ? x2 : x3;
        int lrow = row - (t < 1 ? 0 : t < 2 ? 20000 : t < 3 ? 70000 : 80000);
        float4 v = ((const float4*)(xp + (size_t)lrow * 128))[c4];
        uint2 o;
        o.x = (unsigned int)f2b(v.x) | ((unsigned int)f2b(v.y) << 16);
        o.y = (unsigned int)f2b(v.z) | ((unsigned int)f2b(v.w) << 16);
        ((uint2*)(xb + (size_t)row * 128))[c4] = o;
    }
}

// ---------------------------------------------------------------- fused gather-mean, all relations in one launch
// dot2-based accumulate (1 instr/value), predicated uniform body (no serial tail).
// U tuned per D: quantum U*EPW vs per-relation degrees {50,8,50,40,25,20,3} —
// D=128 (EPW=4): U=2 -> quantum 8 (22% padded slots vs 68% at U=4);
// D=256 (EPW=2): U=4 -> quantum 8 (22%); round-10 showed quantum 16 regresses.
struct GatherCfg {
    const unsigned short* X[7];
    const int* rowptrG;
    const int* csr;
    const float* inv;
    unsigned short* agg;
};

template <int D>
__global__ __launch_bounds__(256)
void gather_all(GatherCfg c)
{
    constexpr int LPE = D / 8;        // lanes per edge (one uint4 = 16B each)
    constexpr int EPW = 64 / LPE;     // edges per wave concurrently (4 or 2)
    constexpr int U   = (D == 128) ? 2 : 4;   // loads in flight per lane (quantum = 8 edges)
    int wid = (blockIdx.x * blockDim.x + threadIdx.x) >> 6;
    if (wid >= 163000) return;
    int l = threadIdx.x & 63;
    int q = l & (LPE - 1);
    int gg = l / LPE;
    int r = relof_n(wid);
    const unsigned short* X = c.X[0];
    if (r==1) X=c.X[1];
    if (r==2) X=c.X[2];
    if (r==3) X=c.X[3];
    if (r==4) X=c.X[4];
    if (r==5) X=c.X[5];
    if (r==6) X=c.X[6];
    const unsigned short* Xq = X + q * 8;
    const int* csr = c.csr;
    int beg = c.rowptrG[wid], end = c.rowptrG[wid + 1];
    float acc[8] = {0.f,0.f,0.f,0.f,0.f,0.f,0.f,0.f};
    if (beg < end) {
        const int last = end - 1;
        for (int it = beg; it < end; it += U * EPW) {
            uint4 v[U]; unsigned int sl[U];
#pragma unroll
            for (int j = 0; j < U; ++j) {
                int idx = it + j * EPW + gg;
                int e = idx < last ? idx : last;      // clamp: overhang re-reads last edge
                int s = csr[e];
                v[j]  = *(const uint4*)(Xq + (size_t)s * D);
                sl[j] = (idx <= last) ? 0x00003F80u : 0u;   // bf16 1.0 selector, 0 if masked
            }
#pragma unroll
            for (int j = 0; j < U; ++j) {
                unsigned int lo = sl[j], hi = sl[j] << 16;
                acc[0] = dot2bf(acc[0], v[j].x, lo);
                acc[1] = dot2bf(acc[1], v[j].x, hi);
                acc[2] = dot2bf(acc[2], v[j].y, lo);
                acc[3] = dot2bf(acc[3], v[j].y, hi);
                acc[4] = dot2bf(acc[4], v[j].z, lo);
                acc[5] = dot2bf(acc[5], v[j].z, hi);
                acc[6] = dot2bf(acc[6], v[j].w, lo);
                acc[7] = dot2bf(acc[7], v[j].w, hi);
            }
        }
    }
#pragma unroll
    for (int k = 0; k < 8; ++k) {
        if (LPE == 16) acc[k] += __shfl_xor(acc[k], 16);
        acc[k] += __shfl_xor(acc[k], 32);
    }
    if (l < LPE) {
        float inv = c.inv[wid];
        uint4 o;
        o.x = (unsigned int)f2b(acc[0]*inv) | ((unsigned int)f2b(acc[1]*inv) << 16);
        o.y = (unsigned int)f2b(acc[2]*inv) | ((unsigned int)f2b(acc[3]*inv) << 16);
        o.z = (unsigned int)f2b(acc[4]*inv) | ((unsigned int)f2b(acc[5]*inv) << 16);
        o.w = (unsigned int)f2b(acc[6]*inv) | ((unsigned int)f2b(acc[7]*inv) << 16);
        *(uint4*)(c.agg + (size_t)wid * D + q * 8) = o;
    }
}

// ---------------------------------------------------------------- weight prep: sum roots, transpose to [N][K] bf16
// (biases dropped: a per-column constant cancels exactly in train-mode BN's v - mu)
__global__ void wtrans_kernel(const float* __restrict__ Wr, const float* __restrict__ Wl,
                              unsigned short* __restrict__ wsumT, unsigned short* __restrict__ WlT,
                              int K)
{
    const int nrel[4]  = {2, 2, 2, 1};
    const int rl[4][2] = {{4,5},{1,6},{0,3},{2,2}};
    int per = 256 * K;
    int tot = 11 * per;
    for (int idx = blockIdx.x * blockDim.x + threadIdx.x; idx < tot;
         idx += gridDim.x * blockDim.x) {
        if (idx < 4 * per) {
            int t = idx / per, rem = idx - t * per;
            int n = rem / K, k = rem - n * K;
            float s = Wr[(size_t)rl[t][0] * per + k * 256 + n];
            if (nrel[t] > 1) s += Wr[(size_t)rl[t][1] * per + k * 256 + n];
            wsumT[idx] = f2b(s);
        } else {
            int j = idx - 4 * per;
            int r = j / per, rem = j - r * per;
            int n = rem / K, k = rem - n * K;
            WlT[j] = f2b(Wl[(size_t)r * per + k * 256 + n]);
        }
    }
}

// ---------------------------------------------------------------- fused MFMA GEMM, 128x256 tile, 8 waves (2x4),
// global_load_lds staging with pre-swizzled source (rule #21), BN-stats fused in epilogue
struct GemmBatch {
    const unsigned short* A0[4];
    const unsigned short* A1[4];
    const unsigned short* A2[4];
    const unsigned short* B0[4];
    const unsigned short* B1[4];
    const unsigned short* B2[4];
    float* outF;
    unsigned short* outB;
    float* stats;
    int R[4]; int bcum[4]; int rowoff[4]; int nsrc[4];
    int K, kshift, outf32;
};

__global__ __launch_bounds__(512, 4)
void gemm_mfma(GemmBatch g)
{
    __shared__ __align__(16) unsigned short Atile[2][128 * 32];   // 16 KB
    __shared__ __align__(16) unsigned short Btile[2][256 * 32];   // 32 KB

    const int tid = threadIdx.x;
    const int bz = blockIdx.x;
    const int t = (bz >= g.bcum[1]) + (bz >= g.bcum[2]) + (bz >= g.bcum[3]);
    const int bm = (bz - g.bcum[t]) << 7;
    const int w = tid >> 6, l = tid & 63;
    const int wr = w >> 2, wc = w & 3;          // 2x4 waves, wave tile 64 rows x 64 cols

    const int R = g.R[t];
    const int K = g.K, kshift = g.kshift, kmask = K - 1;
    const unsigned short* A0t = g.A0[t];
    const unsigned short* A1t = g.A1[t];
    const unsigned short* A2t = g.A2[t];
    const unsigned short* B0t = g.B0[t];
    const unsigned short* B1t = g.B1[t];
    const unsigned short* B2t = g.B2[t];
    const int steps = (g.nsrc[t] * K) >> 5;

    const int rloc = tid >> 2;                                    // 0..127
    const int swz  = (((tid & 3) ^ ((tid >> 3) & 3)) << 3);       // source k-offset (elems)
    const int srowA = min(bm + rloc, R - 1);                      // clamp: garbage only feeds rows >= R
    const int wseg  = w << 9;                                     // w*512 ushorts = 1KB per wave

    auto stage = [&](int st, int buf) {
        int kglob = st << 5;
        int s  = kglob >> kshift;
        int kk = kglob & kmask;
        const unsigned short* As = (s == 0) ? A0t : (s == 1) ? A1t : A2t;
        const unsigned short* Bs = (s == 0) ? B0t : (s == 1) ? B1t : B2t;
        async_ld16(As + (size_t)srowA * K + kk + swz, &Atile[buf][wseg]);
        async_ld16(Bs + (size_t)rloc  * K + kk + swz, &Btile[buf][wseg]);
        async_ld16(Bs + (size_t)(128 + rloc) * K + kk + swz, &Btile[buf][4096 + wseg]);
    };

    f32x4 acc[4][4];
#pragma unroll
    for (int i = 0; i < 4; ++i)
#pragma unroll
        for (int j = 0; j < 4; ++j)
            acc[i][j] = (f32x4){0.f, 0.f, 0.f, 0.f};

    const int ck = l >> 4;
    const int ra = wr * 64 + (l & 15);
    const int aoff = ra * 32 + ((ck ^ ((ra >> 1) & 3)) << 3);
    const int rb = wc * 64 + (l & 15);
    const int boff = rb * 32 + ((ck ^ ((rb >> 1) & 3)) << 3);   // +16 rows keeps swz invariant

    stage(0, 0);
    __syncthreads();
    int cur = 0;
    for (int st = 0; st < steps; ++st) {
        if (st + 1 < steps) stage(st + 1, cur ^ 1);
        const unsigned short* At = Atile[cur];
        const unsigned short* Bt = Btile[cur];
        bf16x8 af[4], bfr[4];
#pragma unroll
        for (int i = 0; i < 4; ++i) {
            af[i]  = *(const bf16x8*)(At + aoff + i * 512);
            bfr[i] = *(const bf16x8*)(Bt + boff + i * 512);
        }
#pragma unroll
        for (int mi = 0; mi < 4; ++mi)
#pragma unroll
            for (int ni = 0; ni < 4; ++ni)
                acc[mi][ni] = __builtin_amdgcn_mfma_f32_16x16x32_bf16(
                    af[mi], bfr[ni], acc[mi][ni], 0, 0, 0);
        __syncthreads();     // drains next-tile global_load_lds + this tile's ds_reads
        cur ^= 1;
    }

    // epilogue: write output + per-column BN partial sums (sum, sumsq)
    const int orow0 = bm + wr * 64 + ((l >> 4) << 2);
    const int ocol0 = wc * 64 + (l & 15);
#pragma unroll
    for (int ni = 0; ni < 4; ++ni) {
        int col = ocol0 + ni * 16;
        float ps = 0.f, pq = 0.f;
#pragma unroll
        for (int mi = 0; mi < 4; ++mi) {
#pragma unroll
            for (int j = 0; j < 4; ++j) {
                int row = orow0 + mi * 16 + j;
                float v = acc[mi][ni][j];
                if (row < R) {
                    size_t o = (size_t)(g.rowoff[t] + row) * 256 + col;
                    if (g.outf32) g.outF[o] = v;
                    else          g.outB[o] = f2b(v);
                } else v = 0.f;
                ps += v; pq += v * v;
            }
        }
        ps += __shfl_xor(ps, 16); ps += __shfl_xor(ps, 32);
        pq += __shfl_xor(pq, 16); pq += __shfl_xor(pq, 32);
        if (l < 16) {
            atomicAdd(&g.stats[t * 512 + col], ps);
            atomicAdd(&g.stats[t * 512 + 256 + col], pq);
        }
    }
}

// ---------------------------------------------------------------- BatchNorm apply (train-mode) + ReLU
template <int F32>
__global__ __launch_bounds__(256)
void bn_apply_all(void* __restrict__ Hv, const float* __restrict__ stats,
                  const float* __restrict__ gg, const float* __restrict__ be)
{
    const int total4 = 83000 * 64;
    for (int i4 = blockIdx.x * blockDim.x + threadIdx.x; i4 < total4;
         i4 += gridDim.x * blockDim.x) {
        int row = i4 >> 6;
        int c4  = (i4 & 63) << 2;
        int t   = typ_of(row);
        float invR = invR_of(t);
        const float* st = stats + t * 512;
        float vin[4];
        if (F32) {
            float4 v = *(const float4*)((const float*)Hv + (size_t)row * 256 + c4);
            vin[0]=v.x; vin[1]=v.y; vin[2]=v.z; vin[3]=v.w;
        } else {
            uint2 u = *(const uint2*)((const unsigned short*)Hv + (size_t)row * 256 + c4);
            vin[0]=blo(u.x); vin[1]=bhi(u.x); vin[2]=blo(u.y); vin[3]=bhi(u.y);
        }
        float vout[4];
#pragma unroll
        for (int k = 0; k < 4; ++k) {
            int c = c4 + k;
            float mu  = st[c] * invR;
            float var = st[256 + c] * invR - mu * mu;
            float sc  = rsqrtf(var + EPS_BN) * gg[c];
            float v   = (vin[k] - mu) * sc + be[c];
            vout[k] = fmaxf(v, 0.f);
        }
        if (F32) {
            float4 o; o.x=vout[0]; o.y=vout[1]; o.z=vout[2]; o.w=vout[3];
            *(float4*)((float*)Hv + (size_t)row * 256 + c4) = o;
        } else {
            uint2 o;
            o.x = (unsigned int)f2b(vout[0]) | ((unsigned int)f2b(vout[1]) << 16);
            o.y = (unsigned int)f2b(vout[2]) | ((unsigned int)f2b(vout[3]) << 16);
            *(uint2*)((unsigned short*)Hv + (size_t)row * 256 + c4) = o;
        }
    }
}

// ---------------------------------------------------------------- host
extern "C" void kernel_launch(void* const* d_in, const int* in_sizes, int n_in,
                              void* d_out, int out_size, void* d_ws, size_t ws_size,
                              hipStream_t stream)
{
    static const int Nn[4]   = {20000, 50000, 10000, 3000};
    static const int roff[4] = {0, 20000, 70000, 80000};
    static const int rst[7]  = {0, 0, 1, 1, 2, 1, 3};
    static const int coff[7] = {0, 10000, 60000, 63000, 73000, 93000, 113000};
    static const int trels[4][2] = {{4,5},{1,6},{0,3},{2,2}};
    static const int tnrel[4]    = {2, 2, 2, 1};
    const int CNT_TOTAL = 163000;

    const float* x[4];
    for (int t = 0; t < 4; ++t) x[t] = (const float*)d_in[t];
    Graph graph;
    for (int i = 0; i < 7; ++i) {
        graph.src[i] = (const int*)d_in[4 + 2 * i];
        graph.dst[i] = (const int*)d_in[5 + 2 * i];
    }
    const float* W1l = (const float*)d_in[18];
    const float* W1r = (const float*)d_in[19];
    const float* W2l = (const float*)d_in[21];
    const float* W2r = (const float*)d_in[22];
    const float* g1  = (const float*)d_in[24];
    const float* be1 = (const float*)d_in[25];
    const float* g2  = (const float*)d_in[26];
    const float* be2 = (const float*)d_in[27];
    float* out = (float*)d_out;
    (void)n_in; (void)in_sizes; (void)out_size; (void)ws_size;

    // ---- workspace carve (~143 MB)
    char* w = (char*)d_ws;
    size_t off = 0;
    auto carve = [&](size_t bytes) -> void* {
        void* p = (void*)(w + off);
        off = (off + bytes + 255) & ~(size_t)255;
        return p;
    };
    int*   icnt    = (int*)carve((size_t)CNT_TOTAL * 4);
    int*   cur     = (int*)carve((size_t)CNT_TOTAL * 4);
    int*   rowptrG = (int*)carve((size_t)(CNT_TOTAL + 1) * 4);
    int*   csr     = (int*)carve((size_t)2500000 * 4);
    int*   scanbuf = (int*)carve((size_t)163840 * 4);
    int*   bsums   = (int*)carve((size_t)256 * 4);
    int*   cuts    = (int*)carve((size_t)8 * 4);
    float* inv     = (float*)carve((size_t)CNT_TOTAL * 4);
    float* stats   = (float*)carve((size_t)2 * 4 * 512 * 4);   // [layer][type][sum|sumsq][256]
    unsigned short* wsumT1 = (unsigned short*)carve((size_t)4 * 256 * 128 * 2);
    unsigned short* WlT1   = (unsigned short*)carve((size_t)7 * 256 * 128 * 2);
    unsigned short* wsumT2 = (unsigned short*)carve((size_t)4 * 256 * 256 * 2);
    unsigned short* WlT2   = (unsigned short*)carve((size_t)7 * 256 * 256 * 2);
    unsigned short* U      = (unsigned short*)carve((size_t)163000 * 256 * 2); // union region
    unsigned short* hb     = (unsigned short*)carve((size_t)83000 * 256 * 2);
    unsigned short* xb    = U;                        // layer-1: bf16 inputs (21.25 MB)
    unsigned short* aggL1 = U + (size_t)83000 * 128;  // layer-1 agg (after xb)
    unsigned short* aggL2 = U;                        // layer-2 agg (xb dead by then)
    float* stats1 = stats;
    float* stats2 = stats + 2048;

    // ---- CSR build (globally-cumulative rowptr; shared by both layers)
    hipMemsetAsync(icnt, 0, (size_t)CNT_TOTAL * 4, stream);
    hipMemsetAsync(stats, 0, (size_t)2 * 4 * 512 * 4, stream);
    count_all<<<2048, 256, 0, stream>>>(graph, icnt);
    scan1<<<160, 1024, 0, stream>>>(icnt, scanbuf, bsums);
    scan2<<<1, 256, 0, stream>>>(bsums);
    scan_fix<<<(CNT_TOTAL + 256) / 256, 256, 0, stream>>>(icnt, scanbuf, bsums,
                                                          rowptrG, cur, inv, cuts);
    fill_all<<<2048, 256, 0, stream>>>(graph, cuts, cur, csr);

    // ---- x -> bf16 (one launch) + weight prep (both layers)
    tob16_all<<<2048, 256, 0, stream>>>(x[0], x[1], x[2], x[3], xb);
    wtrans_kernel<<<1024, 256, 0, stream>>>(W1r, W1l, wsumT1, WlT1, 128);
    wtrans_kernel<<<1024, 256, 0, stream>>>(W2r, W2l, wsumT2, WlT2, 256);

    for (int layer = 0; layer < 2; ++layer) {
        const int K = layer ? 256 : 128;
        const float* gg = layer ? g2  : g1;
        const float* be = layer ? be2 : be1;
        unsigned short* agg = layer ? aggL2 : aggL1;
        unsigned short* wsumT = layer ? wsumT2 : wsumT1;
        unsigned short* WlT   = layer ? WlT2   : WlT1;
        float* st = layer ? stats2 : stats1;

        GatherCfg gc;
        for (int r = 0; r < 7; ++r)
            gc.X[r] = layer ? (hb + (size_t)roff[rst[r]] * 256)
                            : (xb + (size_t)roff[rst[r]] * 128);
        gc.rowptrG = rowptrG; gc.csr = csr; gc.inv = inv; gc.agg = agg;
        if (layer == 0) gather_all<128><<<40750, 256, 0, stream>>>(gc);
        else            gather_all<256><<<40750, 256, 0, stream>>>(gc);

        GemmBatch gb;
        for (int t = 0; t < 4; ++t) {
            gb.A0[t] = layer ? (hb + (size_t)roff[t] * 256) : (xb + (size_t)roff[t] * 128);
            gb.A1[t] = agg + (size_t)coff[trels[t][0]] * K;
            gb.A2[t] = (tnrel[t] > 1) ? (agg + (size_t)coff[trels[t][1]] * K) : gb.A1[t];
            gb.B0[t] = wsumT + (size_t)t * 256 * K;
            gb.B1[t] = WlT + (size_t)trels[t][0] * 256 * K;
            gb.B2[t] = (tnrel[t] > 1) ? (WlT + (size_t)trels[t][1] * 256 * K) : gb.B1[t];
            gb.R[t] = Nn[t];
            gb.rowoff[t] = roff[t];
            gb.nsrc[t] = 1 + tnrel[t];
        }
        gb.bcum[0] = 0; gb.bcum[1] = 157; gb.bcum[2] = 548; gb.bcum[3] = 627;
        gb.outF = out; gb.outB = hb;
        gb.stats = st;
        gb.K = K; gb.kshift = layer ? 8 : 7; gb.outf32 = layer;
        gemm_mfma<<<651, 512, 0, stream>>>(gb);

        if (layer == 0) bn_apply_all<0><<<2048, 256, 0, stream>>>(hb, st, gg, be);
        else            bn_apply_all<1><<<2048, 256, 0, stream>>>(out, st, gg, be);
    }
}

// Round 16
// 769.613 us; speedup vs baseline: 1.0300x; 1.0021x over previous
//
#include <hip/hip_runtime.h>

#define EPS_BN 1e-5f

typedef short bf16x8 __attribute__((ext_vector_type(8)));
typedef float f32x4 __attribute__((ext_vector_type(4)));

__device__ __forceinline__ unsigned short f2b(float f)
{
    union { float f; unsigned int u; } c; c.f = f;
    unsigned int u = c.u + 0x7FFFu + ((c.u >> 16) & 1u);
    return (unsigned short)(u >> 16);
}
__device__ __forceinline__ float blo(unsigned int u)
{
    union { unsigned int u; float f; } c; c.u = u << 16; return c.f;
}
__device__ __forceinline__ float bhi(unsigned int u)
{
    union { unsigned int u; float f; } c; c.u = u & 0xFFFF0000u; return c.f;
}

// acc += a.lo*sel.lo + a.hi*sel.hi  (bf16 pairs, f32 accum) — 1 instr per bf16 value
__device__ __forceinline__ float dot2bf(float acc, unsigned int a, unsigned int sel)
{
    asm("v_dot2_f32_bf16 %0, %1, %2, %0" : "+v"(acc) : "v"(a), "v"(sel));
    return acc;
}

// async global->LDS, 16B per lane; LDS dest = wave-uniform base + lane*16
__device__ __forceinline__ void async_ld16(const unsigned short* g, unsigned short* l)
{
    __builtin_amdgcn_global_load_lds(
        (const __attribute__((address_space(1))) unsigned int*)g,
        (__attribute__((address_space(3))) unsigned int*)l, 16, 0, 0);
}

// relation / type index helpers (branchless compare-sums)
__device__ __forceinline__ int relof_e(int e) {
    return (e>=500000)+(e>=900000)+(e>=1050000)+(e>=1450000)+(e>=1950000)+(e>=2350000);
}
__device__ __forceinline__ int relof_n(int i) {
    return (i>=10000)+(i>=60000)+(i>=63000)+(i>=73000)+(i>=93000)+(i>=113000);
}
__device__ __forceinline__ int eoff_of(int r) {
    return r<1?0 : r<2?500000 : r<3?900000 : r<4?1050000 : r<5?1450000 : r<6?1950000 : 2350000;
}
__device__ __forceinline__ int coff_of(int r) {
    return r<1?0 : r<2?10000 : r<3?60000 : r<4?63000 : r<5?73000 : r<6?93000 : 113000;
}
__device__ __forceinline__ int typ_of(int row) { return (row>=20000)+(row>=70000)+(row>=80000); }
__device__ __forceinline__ float invR_of(int t){ return t<1?5e-5f : t<2?2e-5f : t<3?1e-4f : (1.0f/3000.0f); }

struct Graph { const int* src[7]; const int* dst[7]; };

__device__ __forceinline__ void relptrs(const Graph& g, int r, const int*& sp, const int*& dp)
{
    sp = g.src[0]; dp = g.dst[0];
    if (r==1){sp=g.src[1];dp=g.dst[1];}
    if (r==2){sp=g.src[2];dp=g.dst[2];}
    if (r==3){sp=g.src[3];dp=g.dst[3];}
    if (r==4){sp=g.src[4];dp=g.dst[4];}
    if (r==5){sp=g.src[5];dp=g.dst[5];}
    if (r==6){sp=g.src[6];dp=g.dst[6];}
}

// ---------------------------------------------------------------- degree histogram (all rels, 1 launch)
__global__ void count_all(Graph g, int* __restrict__ icnt)
{
    for (int e = blockIdx.x * blockDim.x + threadIdx.x; e < 2500000; e += gridDim.x * blockDim.x) {
        int r = relof_e(e);
        const int *sp, *dp; relptrs(g, r, sp, dp);
        int le = e - eoff_of(r);
        atomicAdd(&icnt[coff_of(r) + dp[le]], 1);
    }
}

// ---------------------------------------------------------------- 3-phase global scan
__global__ __launch_bounds__(1024)
void scan1(const int* __restrict__ icnt, int* __restrict__ scanbuf, int* __restrict__ bsums)
{
    __shared__ int lds[1024];
    int tid = threadIdx.x;
    int gid = blockIdx.x * 1024 + tid;
    int v = (gid < 163000) ? icnt[gid] : 0;
    lds[tid] = v;
    __syncthreads();
    for (int d = 1; d < 1024; d <<= 1) {
        int t = (tid >= d) ? lds[tid - d] : 0;
        __syncthreads();
        lds[tid] += t;
        __syncthreads();
    }
    scanbuf[gid] = lds[tid];                  // inclusive within block
    if (tid == 1023) bsums[blockIdx.x] = lds[1023];
}

__global__ __launch_bounds__(256)
void scan2(int* __restrict__ bsums)          // exclusive scan of 160 partials, in place
{
    __shared__ int lds[256];
    int tid = threadIdx.x;
    int v = (tid < 160) ? bsums[tid] : 0;
    lds[tid] = v;
    __syncthreads();
    for (int d = 1; d < 256; d <<= 1) {
        int t = (tid >= d) ? lds[tid - d] : 0;
        __syncthreads();
        lds[tid] += t;
        __syncthreads();
    }
    bsums[tid] = tid ? lds[tid - 1] : 0;
}

// fixup: rowptrG (global cumulative), cur (insert cursors), inv (1/max(deg,1)),
// cuts[b] (b=1..7): first dst index whose cumulative edge count reaches b*312500.
// slice(d) = #{b: d >= cut[b]} == min(G(d)/312500, 7) — computable by 7 register compares.
__global__ __launch_bounds__(256)
void scan_fix(const int* __restrict__ icnt, const int* __restrict__ scanbuf,
              const int* __restrict__ bsums, int* __restrict__ rowptrG,
              int* __restrict__ cur, float* __restrict__ inv, int* __restrict__ cuts)
{
    const int QS = 312500;
    int idx = blockIdx.x * blockDim.x + threadIdx.x;
    if (idx > 163000) return;
    int G = bsums[idx >> 10] + ((idx & 1023) ? scanbuf[idx - 1] : 0);
    rowptrG[idx] = G;
    if (idx < 163000) {
        cur[idx] = G;
        inv[idx] = 1.0f / (float)max(icnt[idx], 1);
    }
    if (idx >= 1 && idx <= 163000) {
        int Gp = G - icnt[idx - 1];           // G(idx-1)
#pragma unroll
        for (int b = 1; b <= 7; ++b) {
            int thr = b * QS;
            if (Gp < thr && G >= thr) cuts[b] = idx;   // unique writer per b
        }
    }
}

// ---------------------------------------------------------------- CSR fill, XCD-sliced
// slice computed from 7 register-held cut points (no random table lookup);
// per-dst cursors keep atomic contention spread (round-9 lesson).
__global__ void fill_all(Graph g, const int* __restrict__ cuts,
                         int* __restrict__ cur, int* __restrict__ csr)
{
    const int slice = blockIdx.x & 7;
    const int bper  = gridDim.x >> 3;
    const int bidx  = blockIdx.x >> 3;
    int c1 = cuts[1], c2 = cuts[2], c3 = cuts[3], c4 = cuts[4],
        c5 = cuts[5], c6 = cuts[6], c7 = cuts[7];
    for (int e = bidx * blockDim.x + threadIdx.x; e < 2500000; e += bper * blockDim.x) {
        int r = relof_e(e);
        const int *sp, *dp; relptrs(g, r, sp, dp);
        int le = e - eoff_of(r);
        int gidx = coff_of(r) + dp[le];
        int s = (gidx >= c1) + (gidx >= c2) + (gidx >= c3) + (gidx >= c4)
              + (gidx >= c5) + (gidx >= c6) + (gidx >= c7);
        if (s == slice)
            csr[atomicAdd(&cur[gidx], 1)] = sp[le];
    }
}

// ---------------------------------------------------------------- f32 -> bf16, all 4 types in one launch
__global__ void tob16_all(const float* __restrict__ x0, const float* __restrict__ x1,
                          const float* __restrict__ x2, const float* __restrict__ x3,
                          unsigned short* __restrict__ xb)
{
    const int total = 83000 * 32;             // float4 chunks (128 f32/row)
    for (int i = blockIdx.x * blockDim.x + threadIdx.x; i < total; i += gridDim.x * blockDim.x) {
        int row = i >> 5, c4 = i & 31;
        int t = typ_of(row);
        const float* xp = (t == 0) ? x0 : (t == 1) ? x1 : (t == 2) ? x2 : x3;
        int lrow = row - (t < 1 ? 0 : t < 2 ? 20000 : t < 3 ? 70000 : 80000);
        float4 v = ((const float4*)(xp + (size_t)lrow * 128))[c4];
        uint2 o;
        o.x = (unsigned int)f2b(v.x) | ((unsigned int)f2b(v.y) << 16);
        o.y = (unsigned int)f2b(v.z) | ((unsigned int)f2b(v.w) << 16);
        ((uint2*)(xb + (size_t)row * 128))[c4] = o;
    }
}

// ---------------------------------------------------------------- fused gather-mean, all relations in one launch
// dot2-based accumulate. beg/end are wave-uniform (one row per wave), so full quanta
// run an UNCLAMPED fast path (constant selectors, no compare/cndmask per load);
// at most one masked tail quantum uses the clamped body. FP order identical.
struct GatherCfg {
    const unsigned short* X[7];
    const int* rowptrG;
    const int* csr;
    const float* inv;
    unsigned short* agg;
};

template <int D>
__global__ __launch_bounds__(256)
void gather_all(GatherCfg c)
{
    constexpr int LPE = D / 8;        // lanes per edge (one uint4 = 16B each)
    constexpr int EPW = 64 / LPE;     // edges per wave concurrently (4 or 2)
    constexpr int U   = (D == 128) ? 2 : 4;   // quantum = U*EPW = 8 edges
    int wid = (blockIdx.x * blockDim.x + threadIdx.x) >> 6;
    if (wid >= 163000) return;
    int l = threadIdx.x & 63;
    int q = l & (LPE - 1);
    int gg = l / LPE;
    int r = relof_n(wid);
    const unsigned short* X = c.X[0];
    if (r==1) X=c.X[1];
    if (r==2) X=c.X[2];
    if (r==3) X=c.X[3];
    if (r==4) X=c.X[4];
    if (r==5) X=c.X[5];
    if (r==6) X=c.X[6];
    const unsigned short* Xq = X + q * 8;
    const int* csr = c.csr;
    int beg = c.rowptrG[wid], end = c.rowptrG[wid + 1];
    float acc[8] = {0.f,0.f,0.f,0.f,0.f,0.f,0.f,0.f};
    int it = beg;
    const unsigned int LO = 0x00003F80u, HI = 0x3F800000u;   // bf16 1.0 selectors
    // fast path: full quanta, no clamp, no mask
    for (; it + U * EPW <= end; it += U * EPW) {
        uint4 v[U];
#pragma unroll
        for (int j = 0; j < U; ++j) {
            int s = csr[it + j * EPW + gg];
            v[j] = *(const uint4*)(Xq + (size_t)s * D);
        }
#pragma unroll
        for (int j = 0; j < U; ++j) {
            acc[0] = dot2bf(acc[0], v[j].x, LO);
            acc[1] = dot2bf(acc[1], v[j].x, HI);
            acc[2] = dot2bf(acc[2], v[j].y, LO);
            acc[3] = dot2bf(acc[3], v[j].y, HI);
            acc[4] = dot2bf(acc[4], v[j].z, LO);
            acc[5] = dot2bf(acc[5], v[j].z, HI);
            acc[6] = dot2bf(acc[6], v[j].w, LO);
            acc[7] = dot2bf(acc[7], v[j].w, HI);
        }
    }
    // masked tail: at most one quantum
    if (it < end) {
        const int last = end - 1;
        uint4 v[U]; unsigned int sl[U];
#pragma unroll
        for (int j = 0; j < U; ++j) {
            int idx = it + j * EPW + gg;
            int e = idx < last ? idx : last;      // clamp stays within this row's edges
            int s = csr[e];
            v[j]  = *(const uint4*)(Xq + (size_t)s * D);
            sl[j] = (idx <= last) ? 0x00003F80u : 0u;
        }
#pragma unroll
        for (int j = 0; j < U; ++j) {
            unsigned int lo = sl[j], hi = sl[j] << 16;
            acc[0] = dot2bf(acc[0], v[j].x, lo);
            acc[1] = dot2bf(acc[1], v[j].x, hi);
            acc[2] = dot2bf(acc[2], v[j].y, lo);
            acc[3] = dot2bf(acc[3], v[j].y, hi);
            acc[4] = dot2bf(acc[4], v[j].z, lo);
            acc[5] = dot2bf(acc[5], v[j].z, hi);
            acc[6] = dot2bf(acc[6], v[j].w, lo);
            acc[7] = dot2bf(acc[7], v[j].w, hi);
        }
    }
#pragma unroll
    for (int k = 0; k < 8; ++k) {
        if (LPE == 16) acc[k] += __shfl_xor(acc[k], 16);
        acc[k] += __shfl_xor(acc[k], 32);
    }
    if (l < LPE) {
        float inv = c.inv[wid];
        uint4 o;
        o.x = (unsigned int)f2b(acc[0]*inv) | ((unsigned int)f2b(acc[1]*inv) << 16);
        o.y = (unsigned int)f2b(acc[2]*inv) | ((unsigned int)f2b(acc[3]*inv) << 16);
        o.z = (unsigned int)f2b(acc[4]*inv) | ((unsigned int)f2b(acc[5]*inv) << 16);
        o.w = (unsigned int)f2b(acc[6]*inv) | ((unsigned int)f2b(acc[7]*inv) << 16);
        *(uint4*)(c.agg + (size_t)wid * D + q * 8) = o;
    }
}

// ---------------------------------------------------------------- weight prep: sum roots, transpose to [N][K] bf16
// (biases dropped: a per-column constant cancels exactly in train-mode BN's v - mu)
__global__ void wtrans_kernel(const float* __restrict__ Wr, const float* __restrict__ Wl,
                              unsigned short* __restrict__ wsumT, unsigned short* __restrict__ WlT,
                              int K)
{
    const int nrel[4]  = {2, 2, 2, 1};
    const int rl[4][2] = {{4,5},{1,6},{0,3},{2,2}};
    int per = 256 * K;
    int tot = 11 * per;
    for (int idx = blockIdx.x * blockDim.x + threadIdx.x; idx < tot;
         idx += gridDim.x * blockDim.x) {
        if (idx < 4 * per) {
            int t = idx / per, rem = idx - t * per;
            int n = rem / K, k = rem - n * K;
            float s = Wr[(size_t)rl[t][0] * per + k * 256 + n];
            if (nrel[t] > 1) s += Wr[(size_t)rl[t][1] * per + k * 256 + n];
            wsumT[idx] = f2b(s);
        } else {
            int j = idx - 4 * per;
            int r = j / per, rem = j - r * per;
            int n = rem / K, k = rem - n * K;
            WlT[j] = f2b(Wl[(size_t)r * per + k * 256 + n]);
        }
    }
}

// ---------------------------------------------------------------- fused MFMA GEMM, 128x256 tile, 8 waves (2x4),
// global_load_lds staging with pre-swizzled source (rule #21), BN-stats fused in epilogue
struct GemmBatch {
    const unsigned short* A0[4];
    const unsigned short* A1[4];
    const unsigned short* A2[4];
    const unsigned short* B0[4];
    const unsigned short* B1[4];
    const unsigned short* B2[4];
    float* outF;
    unsigned short* outB;
    float* stats;
    int R[4]; int bcum[4]; int rowoff[4]; int nsrc[4];
    int K, kshift, outf32;
};

__global__ __launch_bounds__(512, 4)
void gemm_mfma(GemmBatch g)
{
    __shared__ __align__(16) unsigned short Atile[2][128 * 32];   // 16 KB
    __shared__ __align__(16) unsigned short Btile[2][256 * 32];   // 32 KB

    const int tid = threadIdx.x;
    const int bz = blockIdx.x;
    const int t = (bz >= g.bcum[1]) + (bz >= g.bcum[2]) + (bz >= g.bcum[3]);
    const int bm = (bz - g.bcum[t]) << 7;
    const int w = tid >> 6, l = tid & 63;
    const int wr = w >> 2, wc = w & 3;          // 2x4 waves, wave tile 64 rows x 64 cols

    const int R = g.R[t];
    const int K = g.K, kshift = g.kshift, kmask = K - 1;
    const unsigned short* A0t = g.A0[t];
    const unsigned short* A1t = g.A1[t];
    const unsigned short* A2t = g.A2[t];
    const unsigned short* B0t = g.B0[t];
    const unsigned short* B1t = g.B1[t];
    const unsigned short* B2t = g.B2[t];
    const int steps = (g.nsrc[t] * K) >> 5;

    const int rloc = tid >> 2;                                    // 0..127
    const int swz  = (((tid & 3) ^ ((tid >> 3) & 3)) << 3);       // source k-offset (elems)
    const int srowA = min(bm + rloc, R - 1);                      // clamp: garbage only feeds rows >= R
    const int wseg  = w << 9;                                     // w*512 ushorts = 1KB per wave

    auto stage = [&](int st, int buf) {
        int kglob = st << 5;
        int s  = kglob >> kshift;
        int kk = kglob & kmask;
        const unsigned short* As = (s == 0) ? A0t : (s == 1) ? A1t : A2t;
        const unsigned short* Bs = (s == 0) ? B0t : (s == 1) ? B1t : B2t;
        async_ld16(As + (size_t)srowA * K + kk + swz, &Atile[buf][wseg]);
        async_ld16(Bs + (size_t)rloc  * K + kk + swz, &Btile[buf][wseg]);
        async_ld16(Bs + (size_t)(128 + rloc) * K + kk + swz, &Btile[buf][4096 + wseg]);
    };

    f32x4 acc[4][4];
#pragma unroll
    for (int i = 0; i < 4; ++i)
#pragma unroll
        for (int j = 0; j < 4; ++j)
            acc[i][j] = (f32x4){0.f, 0.f, 0.f, 0.f};

    const int ck = l >> 4;
    const int ra = wr * 64 + (l & 15);
    const int aoff = ra * 32 + ((ck ^ ((ra >> 1) & 3)) << 3);
    const int rb = wc * 64 + (l & 15);
    const int boff = rb * 32 + ((ck ^ ((rb >> 1) & 3)) << 3);   // +16 rows keeps swz invariant

    stage(0, 0);
    __syncthreads();
    int cur = 0;
    for (int st = 0; st < steps; ++st) {
        if (st + 1 < steps) stage(st + 1, cur ^ 1);
        const unsigned short* At = Atile[cur];
        const unsigned short* Bt = Btile[cur];
        bf16x8 af[4], bfr[4];
#pragma unroll
        for (int i = 0; i < 4; ++i) {
            af[i]  = *(const bf16x8*)(At + aoff + i * 512);
            bfr[i] = *(const bf16x8*)(Bt + boff + i * 512);
        }
#pragma unroll
        for (int mi = 0; mi < 4; ++mi)
#pragma unroll
            for (int ni = 0; ni < 4; ++ni)
                acc[mi][ni] = __builtin_amdgcn_mfma_f32_16x16x32_bf16(
                    af[mi], bfr[ni], acc[mi][ni], 0, 0, 0);
        __syncthreads();     // drains next-tile global_load_lds + this tile's ds_reads
        cur ^= 1;
    }

    // epilogue: write output + per-column BN partial sums (sum, sumsq)
    const int orow0 = bm + wr * 64 + ((l >> 4) << 2);
    const int ocol0 = wc * 64 + (l & 15);
#pragma unroll
    for (int ni = 0; ni < 4; ++ni) {
        int col = ocol0 + ni * 16;
        float ps = 0.f, pq = 0.f;
#pragma unroll
        for (int mi = 0; mi < 4; ++mi) {
#pragma unroll
            for (int j = 0; j < 4; ++j) {
                int row = orow0 + mi * 16 + j;
                float v = acc[mi][ni][j];
                if (row < R) {
                    size_t o = (size_t)(g.rowoff[t] + row) * 256 + col;
                    if (g.outf32) g.outF[o] = v;
                    else          g.outB[o] = f2b(v);
                } else v = 0.f;
                ps += v; pq += v * v;
            }
        }
        ps += __shfl_xor(ps, 16); ps += __shfl_xor(ps, 32);
        pq += __shfl_xor(pq, 16); pq += __shfl_xor(pq, 32);
        if (l < 16) {
            atomicAdd(&g.stats[t * 512 + col], ps);
            atomicAdd(&g.stats[t * 512 + 256 + col], pq);
        }
    }
}

// ---------------------------------------------------------------- BatchNorm apply (train-mode) + ReLU
template <int F32>
__global__ __launch_bounds__(256)
void bn_apply_all(void* __restrict__ Hv, const float* __restrict__ stats,
                  const float* __restrict__ gg, const float* __restrict__ be)
{
    const int total4 = 83000 * 64;
    for (int i4 = blockIdx.x * blockDim.x + threadIdx.x; i4 < total4;
         i4 += gridDim.x * blockDim.x) {
        int row = i4 >> 6;
        int c4  = (i4 & 63) << 2;
        int t   = typ_of(row);
        float invR = invR_of(t);
        const float* st = stats + t * 512;
        float vin[4];
        if (F32) {
            float4 v = *(const float4*)((const float*)Hv + (size_t)row * 256 + c4);
            vin[0]=v.x; vin[1]=v.y; vin[2]=v.z; vin[3]=v.w;
        } else {
            uint2 u = *(const uint2*)((const unsigned short*)Hv + (size_t)row * 256 + c4);
            vin[0]=blo(u.x); vin[1]=bhi(u.x); vin[2]=blo(u.y); vin[3]=bhi(u.y);
        }
        float vout[4];
#pragma unroll
        for (int k = 0; k < 4; ++k) {
            int c = c4 + k;
            float mu  = st[c] * invR;
            float var = st[256 + c] * invR - mu * mu;
            float sc  = rsqrtf(var + EPS_BN) * gg[c];
            float v   = (vin[k] - mu) * sc + be[c];
            vout[k] = fmaxf(v, 0.f);
        }
        if (F32) {
            float4 o; o.x=vout[0]; o.y=vout[1]; o.z=vout[2]; o.w=vout[3];
            *(float4*)((float*)Hv + (size_t)row * 256 + c4) = o;
        } else {
            uint2 o;
            o.x = (unsigned int)f2b(vout[0]) | ((unsigned int)f2b(vout[1]) << 16);
            o.y = (unsigned int)f2b(vout[2]) | ((unsigned int)f2b(vout[3]) << 16);
            *(uint2*)((unsigned short*)Hv + (size_t)row * 256 + c4) = o;
        }
    }
}

// ---------------------------------------------------------------- host
extern "C" void kernel_launch(void* const* d_in, const int* in_sizes, int n_in,
                              void* d_out, int out_size, void* d_ws, size_t ws_size,
                              hipStream_t stream)
{
    static const int Nn[4]   = {20000, 50000, 10000, 3000};
    static const int roff[4] = {0, 20000, 70000, 80000};
    static const int rst[7]  = {0, 0, 1, 1, 2, 1, 3};
    static const int coff[7] = {0, 10000, 60000, 63000, 73000, 93000, 113000};
    static const int trels[4][2] = {{4,5},{1,6},{0,3},{2,2}};
    static const int tnrel[4]    = {2, 2, 2, 1};
    const int CNT_TOTAL = 163000;

    const float* x[4];
    for (int t = 0; t < 4; ++t) x[t] = (const float*)d_in[t];
    Graph graph;
    for (int i = 0; i < 7; ++i) {
        graph.src[i] = (const int*)d_in[4 + 2 * i];
        graph.dst[i] = (const int*)d_in[5 + 2 * i];
    }
    const float* W1l = (const float*)d_in[18];
    const float* W1r = (const float*)d_in[19];
    const float* W2l = (const float*)d_in[21];
    const float* W2r = (const float*)d_in[22];
    const float* g1  = (const float*)d_in[24];
    const float* be1 = (const float*)d_in[25];
    const float* g2  = (const float*)d_in[26];
    const float* be2 = (const float*)d_in[27];
    float* out = (float*)d_out;
    (void)n_in; (void)in_sizes; (void)out_size; (void)ws_size;

    // ---- workspace carve (~143 MB)
    char* w = (char*)d_ws;
    size_t off = 0;
    auto carve = [&](size_t bytes) -> void* {
        void* p = (void*)(w + off);
        off = (off + bytes + 255) & ~(size_t)255;
        return p;
    };
    int*   icnt    = (int*)carve((size_t)CNT_TOTAL * 4);
    int*   cur     = (int*)carve((size_t)CNT_TOTAL * 4);
    int*   rowptrG = (int*)carve((size_t)(CNT_TOTAL + 1) * 4);
    int*   csr     = (int*)carve((size_t)2500000 * 4);
    int*   scanbuf = (int*)carve((size_t)163840 * 4);
    int*   bsums   = (int*)carve((size_t)256 * 4);
    int*   cuts    = (int*)carve((size_t)8 * 4);
    float* inv     = (float*)carve((size_t)CNT_TOTAL * 4);
    float* stats   = (float*)carve((size_t)2 * 4 * 512 * 4);   // [layer][type][sum|sumsq][256]
    unsigned short* wsumT1 = (unsigned short*)carve((size_t)4 * 256 * 128 * 2);
    unsigned short* WlT1   = (unsigned short*)carve((size_t)7 * 256 * 128 * 2);
    unsigned short* wsumT2 = (unsigned short*)carve((size_t)4 * 256 * 256 * 2);
    unsigned short* WlT2   = (unsigned short*)carve((size_t)7 * 256 * 256 * 2);
    unsigned short* U      = (unsigned short*)carve((size_t)163000 * 256 * 2); // union region
    unsigned short* hb     = (unsigned short*)carve((size_t)83000 * 256 * 2);
    unsigned short* xb    = U;                        // layer-1: bf16 inputs (21.25 MB)
    unsigned short* aggL1 = U + (size_t)83000 * 128;  // layer-1 agg (after xb)
    unsigned short* aggL2 = U;                        // layer-2 agg (xb dead by then)
    float* stats1 = stats;
    float* stats2 = stats + 2048;

    // ---- CSR build (globally-cumulative rowptr; shared by both layers)
    hipMemsetAsync(icnt, 0, (size_t)CNT_TOTAL * 4, stream);
    hipMemsetAsync(stats, 0, (size_t)2 * 4 * 512 * 4, stream);
    count_all<<<2048, 256, 0, stream>>>(graph, icnt);
    scan1<<<160, 1024, 0, stream>>>(icnt, scanbuf, bsums);
    scan2<<<1, 256, 0, stream>>>(bsums);
    scan_fix<<<(CNT_TOTAL + 256) / 256, 256, 0, stream>>>(icnt, scanbuf, bsums,
                                                          rowptrG, cur, inv, cuts);
    fill_all<<<2048, 256, 0, stream>>>(graph, cuts, cur, csr);

    // ---- x -> bf16 (one launch) + weight prep (both layers)
    tob16_all<<<2048, 256, 0, stream>>>(x[0], x[1], x[2], x[3], xb);
    wtrans_kernel<<<1024, 256, 0, stream>>>(W1r, W1l, wsumT1, WlT1, 128);
    wtrans_kernel<<<1024, 256, 0, stream>>>(W2r, W2l, wsumT2, WlT2, 256);

    for (int layer = 0; layer < 2; ++layer) {
        const int K = layer ? 256 : 128;
        const float* gg = layer ? g2  : g1;
        const float* be = layer ? be2 : be1;
        unsigned short* agg = layer ? aggL2 : aggL1;
        unsigned short* wsumT = layer ? wsumT2 : wsumT1;
        unsigned short* WlT   = layer ? WlT2   : WlT1;
        float* st = layer ? stats2 : stats1;

        GatherCfg gc;
        for (int r = 0; r < 7; ++r)
            gc.X[r] = layer ? (hb + (size_t)roff[rst[r]] * 256)
                            : (xb + (size_t)roff[rst[r]] * 128);
        gc.rowptrG = rowptrG; gc.csr = csr; gc.inv = inv; gc.agg = agg;
        if (layer == 0) gather_all<128><<<40750, 256, 0, stream>>>(gc);
        else            gather_all<256><<<40750, 256, 0, stream>>>(gc);

        GemmBatch gb;
        for (int t = 0; t < 4; ++t) {
            gb.A0[t] = layer ? (hb + (size_t)roff[t] * 256) : (xb + (size_t)roff[t] * 128);
            gb.A1[t] = agg + (size_t)coff[trels[t][0]] * K;
            gb.A2[t] = (tnrel[t] > 1) ? (agg + (size_t)coff[trels[t][1]] * K) : gb.A1[t];
            gb.B0[t] = wsumT + (size_t)t * 256 * K;
            gb.B1[t] = WlT + (size_t)trels[t][0] * 256 * K;
            gb.B2[t] = (tnrel[t] > 1) ? (WlT + (size_t)trels[t][1] * 256 * K) : gb.B1[t];
            gb.R[t] = Nn[t];
            gb.rowoff[t] = roff[t];
            gb.nsrc[t] = 1 + tnrel[t];
        }
        gb.bcum[0] = 0; gb.bcum[1] = 157; gb.bcum[2] = 548; gb.bcum[3] = 627;
        gb.outF = out; gb.outB = hb;
        gb.stats = st;
        gb.K = K; gb.kshift = layer ? 8 : 7; gb.outf32 = layer;
        gemm_mfma<<<651, 512, 0, stream>>>(gb);

        if (layer == 0) bn_apply_all<0><<<2048, 256, 0, stream>>>(hb, st, gg, be);
        else            bn_apply_all<1><<<2048, 256, 0, stream>>>(out, st, gg, be);
    }
}